// Round 1
// baseline (590.219 us; speedup 1.0000x reference)
//
#include <hip/hip_runtime.h>
#include <hip/hip_bf16.h>
#include <stdint.h>

#define D 128
#define BM 64
#define SCAN_B 1024

typedef __attribute__((ext_vector_type(8))) short bf16x8;
typedef __attribute__((ext_vector_type(4))) short short4_t;
typedef __attribute__((ext_vector_type(4))) float f32x4;

static __device__ __forceinline__ short f2bf(float f) {
  uint32_t u = __builtin_bit_cast(uint32_t, f);
  u += 0x7fffu + ((u >> 16) & 1u);   // round-to-nearest-even
  return (short)(u >> 16);
}

// ---------------- CSR build ----------------

__global__ void k_zero(int* __restrict__ p, int n) {
  int i = blockIdx.x * blockDim.x + threadIdx.x;
  if (i < n) p[i] = 0;
}

__global__ void k_count(const int* __restrict__ dst, int* __restrict__ cnt, int E) {
  int e = blockIdx.x * blockDim.x + threadIdx.x;
  if (e < E) atomicAdd(&cnt[dst[e]], 1);
}

__global__ __launch_bounds__(SCAN_B) void k_scan1(const int* __restrict__ cnt,
                                                  int* __restrict__ off,
                                                  int* __restrict__ csum, int N) {
  __shared__ int s[SCAN_B];
  int t = threadIdx.x;
  int i = blockIdx.x * SCAN_B + t;
  int v = (i < N) ? cnt[i] : 0;
  s[t] = v;
  __syncthreads();
  for (int dd = 1; dd < SCAN_B; dd <<= 1) {
    int a = (t >= dd) ? s[t - dd] : 0;
    __syncthreads();
    s[t] += a;
    __syncthreads();
  }
  if (i < N) off[i] = s[t] - v;          // exclusive within chunk
  if (t == SCAN_B - 1) csum[blockIdx.x] = s[t];
}

__global__ __launch_bounds__(SCAN_B) void k_scan2(int* __restrict__ csum, int NC) {
  __shared__ int s[SCAN_B];
  int t = threadIdx.x;
  int v = (t < NC) ? csum[t] : 0;
  s[t] = v;
  __syncthreads();
  for (int dd = 1; dd < SCAN_B; dd <<= 1) {
    int a = (t >= dd) ? s[t - dd] : 0;
    __syncthreads();
    s[t] += a;
    __syncthreads();
  }
  if (t < NC) csum[t] = s[t] - v;        // exclusive chunk bases
}

__global__ __launch_bounds__(SCAN_B) void k_scan3(int* __restrict__ off,
                                                  const int* __restrict__ csum,
                                                  int N, int E) {
  int i = blockIdx.x * SCAN_B + threadIdx.x;
  if (i < N) off[i] += csum[blockIdx.x];
  if (i == 0) off[N] = E;
}

__global__ void k_fill(const int* __restrict__ src, const int* __restrict__ dst,
                       const float* __restrict__ wgt, const int* __restrict__ off,
                       int* __restrict__ cur, int* __restrict__ s_srt,
                       float* __restrict__ w_srt, int E) {
  int e = blockIdx.x * blockDim.x + threadIdx.x;
  if (e < E) {
    int dn = dst[e];
    int slot = atomicAdd(&cur[dn], 1);
    int p = off[dn] + slot;
    s_srt[p] = src[e];
    w_srt[p] = wgt[e];
  }
}

// ---------------- weight prep: BT[n][k] bf16, n in [0,256): [W | Wloop]^T ----------------

__global__ void k_prepB(const float* __restrict__ W, const float* __restrict__ Wl,
                        short* __restrict__ BT) {
  int idx = blockIdx.x * 256 + threadIdx.x;      // 2*D*D = 32768
  if (idx >= 2 * D * D) return;
  int n = idx >> 7, k = idx & (D - 1);
  float v = (n < D) ? W[k * D + n] : Wl[k * D + (n - D)];
  BT[idx] = f2bf(v);
}

// ---------------- fused GEMM: support = A@W ; init = A@Wloop + b ----------------
// A fp32 [M][128]; BT bf16 [256][128] (cols 0..127 -> W, 128..255 -> Wloop)
// block = 256 threads (4 waves); tile BM=64 rows; wave w owns cols [w*64, w*64+64)

__global__ __launch_bounds__(256) void k_gemm(const float* __restrict__ A,
                                              const short* __restrict__ BT,
                                              const float* __restrict__ bias,
                                              float* __restrict__ support,
                                              float* __restrict__ init, int M) {
  __shared__ short As[BM * D];                   // 16 KB, XOR-swizzled
  const int t = threadIdx.x;
  const int l = t & 63;
  const int w = t >> 6;
  const int m0 = blockIdx.x * BM;

  // B fragments in registers: [cf][ks], col = w*64 + cf*16 + (l&15)
  bf16x8 bfrag[4][4];
  const int colbase = w * 64 + (l & 15);
#pragma unroll
  for (int cf = 0; cf < 4; ++cf) {
    const short* p = BT + (colbase + cf * 16) * D + (l >> 4) * 8;
#pragma unroll
    for (int ks = 0; ks < 4; ++ks) bfrag[cf][ks] = *(const bf16x8*)(p + ks * 32);
  }

  // stage A tile -> bf16 LDS (swizzled: short index ^= (row&7)<<3)
#pragma unroll
  for (int i = 0; i < 8; ++i) {
    int id = t + i * 256;                        // 0..2047
    int row = id >> 5, c4 = id & 31;
    int gr = m0 + row;
    float4 v;
    if (gr < M) v = *(const float4*)(A + (size_t)gr * D + c4 * 4);
    else { v.x = v.y = v.z = v.w = 0.f; }
    short4_t s4 = { f2bf(v.x), f2bf(v.y), f2bf(v.z), f2bf(v.w) };
    int sidx = row * D + ((c4 * 4) ^ ((row & 7) << 3));
    *(short4_t*)(As + sidx) = s4;
  }
  __syncthreads();

  f32x4 acc[4][4] = {};                          // [rf][cf]
#pragma unroll
  for (int ks = 0; ks < 4; ++ks) {
    bf16x8 afrag[4];
    int kcol = ks * 32 + (l >> 4) * 8;
#pragma unroll
    for (int rf = 0; rf < 4; ++rf) {
      int row = rf * 16 + (l & 15);
      afrag[rf] = *(const bf16x8*)(As + row * D + (kcol ^ ((row & 7) << 3)));
    }
#pragma unroll
    for (int rf = 0; rf < 4; ++rf)
#pragma unroll
      for (int cf = 0; cf < 4; ++cf)
        acc[rf][cf] = __builtin_amdgcn_mfma_f32_16x16x32_bf16(
            afrag[rf], bfrag[cf][ks], acc[rf][cf], 0, 0, 0);
  }

  // epilogue: waves 0,1 -> support cols 0..127 ; waves 2,3 -> init cols 0..127 (+bias)
  const bool isInit = (w >= 2);
  float* op = isInit ? init : support;
#pragma unroll
  for (int cf = 0; cf < 4; ++cf) {
    int c = colbase + cf * 16;
    int oc = isInit ? (c - D) : c;
    float bv = isInit ? bias[oc] : 0.f;
#pragma unroll
    for (int rf = 0; rf < 4; ++rf) {
      int rbase = m0 + rf * 16 + (l >> 4) * 4;
#pragma unroll
      for (int j = 0; j < 4; ++j) {
        int r = rbase + j;
        if (r < M) op[(size_t)r * D + oc] = acc[rf][cf][j] + bv;
      }
    }
  }
}

// ---------------- aggregation: io[n] = io[n] + sum_j support[src_j]*w_j (opt residual) ----------------

__global__ __launch_bounds__(128) void k_agg(const float* __restrict__ sup,
                                             const int* __restrict__ off,
                                             const int* __restrict__ s_srt,
                                             const float* __restrict__ w_srt,
                                             const float* __restrict__ resid,
                                             float* __restrict__ io, int N) {
  int n = blockIdx.x;
  int d = threadIdx.x;
  int beg = off[n], end = off[n + 1];
  float acc = 0.f;
  int j = beg;
  for (; j + 1 < end; j += 2) {
    int s0 = s_srt[j], s1 = s_srt[j + 1];
    float w0 = w_srt[j], w1 = w_srt[j + 1];
    acc += sup[(size_t)s0 * D + d] * w0 + sup[(size_t)s1 * D + d] * w1;
  }
  if (j < end) acc += sup[(size_t)s_srt[j] * D + d] * w_srt[j];
  size_t o = (size_t)n * D + d;
  float v = io[o] + acc;
  if (resid) v = (v + resid[o]) * 0.5f;
  io[o] = v;
}

// ---------------- launch ----------------

extern "C" void kernel_launch(void* const* d_in, const int* in_sizes, int n_in,
                              void* d_out, int out_size, void* d_ws, size_t ws_size,
                              hipStream_t stream) {
  const float* x   = (const float*)d_in[0];
  const int*   ei  = (const int*)d_in[1];
  const float* ew  = (const float*)d_in[2];
  const float* W1  = (const float*)d_in[3];
  const float* Wl1 = (const float*)d_in[4];
  const float* b1  = (const float*)d_in[5];
  const float* W2  = (const float*)d_in[6];
  const float* Wl2 = (const float*)d_in[7];
  const float* b2  = (const float*)d_in[8];
  float* out = (float*)d_out;

  const int N = in_sizes[0] / D;
  const int E = in_sizes[1] / 2;
  const int* src = ei;
  const int* dst = ei + E;

  // workspace layout
  float* sup = (float*)d_ws;                 // N*D floats (51.2 MB)
  float* h1  = sup + (size_t)N * D;          // N*D floats (51.2 MB)
  short* BT1 = (short*)(h1 + (size_t)N * D); // 2*D*D bf16 (64 KB)
  short* BT2 = BT1 + 2 * D * D;              // 64 KB
  int* cnt   = (int*)(BT2 + 2 * D * D);      // N ints
  int* off   = cnt + N;                      // N+1 ints
  int* csum  = off + (N + 1);                // <=1024 ints
  int* s_srt = csum + SCAN_B;                // E ints
  float* w_srt = (float*)(s_srt + E);        // E floats

  const int nchunk = (N + SCAN_B - 1) / SCAN_B;

  // weight prep
  k_prepB<<<(2 * D * D + 255) / 256, 256, 0, stream>>>(W1, Wl1, BT1);
  k_prepB<<<(2 * D * D + 255) / 256, 256, 0, stream>>>(W2, Wl2, BT2);

  // CSR build (shared by both layers)
  k_zero<<<(N + 255) / 256, 256, 0, stream>>>(cnt, N);
  k_count<<<(E + 255) / 256, 256, 0, stream>>>(dst, cnt, E);
  k_scan1<<<nchunk, SCAN_B, 0, stream>>>(cnt, off, csum, N);
  k_scan2<<<1, SCAN_B, 0, stream>>>(csum, nchunk);
  k_scan3<<<nchunk, SCAN_B, 0, stream>>>(off, csum, N, E);
  k_zero<<<(N + 255) / 256, 256, 0, stream>>>(cnt, N);
  k_fill<<<(E + 255) / 256, 256, 0, stream>>>(src, dst, ew, off, cnt, s_srt, w_srt, E);

  const int mblocks = (N + BM - 1) / BM;

  // layer 1: support = x@W1 ; h1 = x@Wloop1 + b1 ; h1 += agg
  k_gemm<<<mblocks, 256, 0, stream>>>(x, BT1, b1, sup, h1, N);
  k_agg<<<N, 128, 0, stream>>>(sup, off, s_srt, w_srt, nullptr, h1, N);

  // layer 2: support = h1@W2 ; out = h1@Wloop2 + b2 ; out = (x + out + agg)*0.5
  k_gemm<<<mblocks, 256, 0, stream>>>(h1, BT2, b2, sup, out, N);
  k_agg<<<N, 128, 0, stream>>>(sup, off, s_srt, w_srt, x, out, N);
}

// Round 2
// 499.345 us; speedup vs baseline: 1.1820x; 1.1820x over previous
//
#include <hip/hip_runtime.h>
#include <hip/hip_bf16.h>
#include <stdint.h>

#define D 128
#define BM 64
#define SCAN_B 1024

typedef __attribute__((ext_vector_type(8))) short bf16x8;
typedef __attribute__((ext_vector_type(4))) short short4_t;
typedef __attribute__((ext_vector_type(4))) float f32x4;
typedef unsigned int uint32;

static __device__ __forceinline__ short f2bf(float f) {
  uint32_t u = __builtin_bit_cast(uint32_t, f);
  u += 0x7fffu + ((u >> 16) & 1u);   // round-to-nearest-even
  return (short)(u >> 16);
}

// ---------------- CSR build ----------------

__global__ void k_zero(int* __restrict__ p, int n) {
  int i = blockIdx.x * blockDim.x + threadIdx.x;
  if (i < n) p[i] = 0;
}

__global__ void k_count(const int* __restrict__ dst, int* __restrict__ cnt, int E) {
  int e = blockIdx.x * blockDim.x + threadIdx.x;
  if (e < E) atomicAdd(&cnt[dst[e]], 1);
}

__global__ __launch_bounds__(SCAN_B) void k_scan1(const int* __restrict__ cnt,
                                                  int* __restrict__ off,
                                                  int* __restrict__ csum, int N) {
  __shared__ int s[SCAN_B];
  int t = threadIdx.x;
  int i = blockIdx.x * SCAN_B + t;
  int v = (i < N) ? cnt[i] : 0;
  s[t] = v;
  __syncthreads();
  for (int dd = 1; dd < SCAN_B; dd <<= 1) {
    int a = (t >= dd) ? s[t - dd] : 0;
    __syncthreads();
    s[t] += a;
    __syncthreads();
  }
  if (i < N) off[i] = s[t] - v;          // exclusive within chunk
  if (t == SCAN_B - 1) csum[blockIdx.x] = s[t];
}

__global__ __launch_bounds__(SCAN_B) void k_scan2(int* __restrict__ csum, int NC) {
  __shared__ int s[SCAN_B];
  int t = threadIdx.x;
  int v = (t < NC) ? csum[t] : 0;
  s[t] = v;
  __syncthreads();
  for (int dd = 1; dd < SCAN_B; dd <<= 1) {
    int a = (t >= dd) ? s[t - dd] : 0;
    __syncthreads();
    s[t] += a;
    __syncthreads();
  }
  if (t < NC) csum[t] = s[t] - v;        // exclusive chunk bases
}

__global__ __launch_bounds__(SCAN_B) void k_scan3(int* __restrict__ off,
                                                  const int* __restrict__ csum,
                                                  int N, int E) {
  int i = blockIdx.x * SCAN_B + threadIdx.x;
  if (i < N) off[i] += csum[blockIdx.x];
  if (i == 0) off[N] = E;
}

__global__ void k_fill(const int* __restrict__ src, const int* __restrict__ dst,
                       const float* __restrict__ wgt, const int* __restrict__ off,
                       int* __restrict__ cur, int2* __restrict__ pairs, int E) {
  int e = blockIdx.x * blockDim.x + threadIdx.x;
  if (e < E) {
    int dn = dst[e];
    int slot = atomicAdd(&cur[dn], 1);
    int p = off[dn] + slot;
    pairs[p] = make_int2(src[e], __builtin_bit_cast(int, wgt[e]));
  }
}

// ---------------- weight prep: BT[n][k] bf16, n in [0,256): [W | Wloop]^T ----------------

__global__ void k_prepB(const float* __restrict__ W, const float* __restrict__ Wl,
                        short* __restrict__ BT) {
  int idx = blockIdx.x * 256 + threadIdx.x;      // 2*D*D = 32768
  if (idx >= 2 * D * D) return;
  int n = idx >> 7, k = idx & (D - 1);
  float v = (n < D) ? W[k * D + n] : Wl[k * D + (n - D)];
  BT[idx] = f2bf(v);
}

// ---------------- fused GEMM: support(bf16) = A@W ; init(f32) = A@Wloop + b ----------------
// A fp32 [M][128]; BT bf16 [256][128] (cols 0..127 -> W, 128..255 -> Wloop)
// block = 256 threads (4 waves); tile BM=64 rows; wave w owns cols [w*64, w*64+64)

__global__ __launch_bounds__(256) void k_gemm(const float* __restrict__ A,
                                              const short* __restrict__ BT,
                                              const float* __restrict__ bias,
                                              unsigned short* __restrict__ support,
                                              float* __restrict__ init, int M) {
  __shared__ short As[BM * D];                   // 16 KB, XOR-swizzled
  const int t = threadIdx.x;
  const int l = t & 63;
  const int w = t >> 6;
  const int m0 = blockIdx.x * BM;

  // B fragments in registers: [cf][ks], col = w*64 + cf*16 + (l&15)
  bf16x8 bfrag[4][4];
  const int colbase = w * 64 + (l & 15);
#pragma unroll
  for (int cf = 0; cf < 4; ++cf) {
    const short* p = BT + (colbase + cf * 16) * D + (l >> 4) * 8;
#pragma unroll
    for (int ks = 0; ks < 4; ++ks) bfrag[cf][ks] = *(const bf16x8*)(p + ks * 32);
  }

  // stage A tile -> bf16 LDS (swizzled: short index ^= (row&7)<<3)
#pragma unroll
  for (int i = 0; i < 8; ++i) {
    int id = t + i * 256;                        // 0..2047
    int row = id >> 5, c4 = id & 31;
    int gr = m0 + row;
    float4 v;
    if (gr < M) v = *(const float4*)(A + (size_t)gr * D + c4 * 4);
    else { v.x = v.y = v.z = v.w = 0.f; }
    short4_t s4 = { f2bf(v.x), f2bf(v.y), f2bf(v.z), f2bf(v.w) };
    int sidx = row * D + ((c4 * 4) ^ ((row & 7) << 3));
    *(short4_t*)(As + sidx) = s4;
  }
  __syncthreads();

  f32x4 acc[4][4] = {};                          // [rf][cf]
#pragma unroll
  for (int ks = 0; ks < 4; ++ks) {
    bf16x8 afrag[4];
    int kcol = ks * 32 + (l >> 4) * 8;
#pragma unroll
    for (int rf = 0; rf < 4; ++rf) {
      int row = rf * 16 + (l & 15);
      afrag[rf] = *(const bf16x8*)(As + row * D + (kcol ^ ((row & 7) << 3)));
    }
#pragma unroll
    for (int rf = 0; rf < 4; ++rf)
#pragma unroll
      for (int cf = 0; cf < 4; ++cf)
        acc[rf][cf] = __builtin_amdgcn_mfma_f32_16x16x32_bf16(
            afrag[rf], bfrag[cf][ks], acc[rf][cf], 0, 0, 0);
  }

  // epilogue: waves 0,1 -> support (bf16) cols 0..127 ; waves 2,3 -> init (f32) + bias
  const bool isInit = (w >= 2);
#pragma unroll
  for (int cf = 0; cf < 4; ++cf) {
    int c = colbase + cf * 16;
    int oc = isInit ? (c - D) : c;
    float bv = isInit ? bias[oc] : 0.f;
#pragma unroll
    for (int rf = 0; rf < 4; ++rf) {
      int rbase = m0 + rf * 16 + (l >> 4) * 4;
#pragma unroll
      for (int j = 0; j < 4; ++j) {
        int r = rbase + j;
        if (r < M) {
          if (isInit) init[(size_t)r * D + oc] = acc[rf][cf][j] + bv;
          else        support[(size_t)r * D + oc] = (unsigned short)f2bf(acc[rf][cf][j]);
        }
      }
    }
  }
}

// ---------------- aggregation: io[n] += sum_j bf16(support[src_j])*w_j (opt residual) ----------------
// one wave per node; lane l handles channels 2l, 2l+1 (one uint = 2 bf16)

__global__ __launch_bounds__(256) void k_agg(const uint32* __restrict__ sup,
                                             const int* __restrict__ off,
                                             const int2* __restrict__ pairs,
                                             const float2* __restrict__ resid,
                                             float2* __restrict__ io, int N) {
  int node = blockIdx.x * 4 + (threadIdx.x >> 6);
  if (node >= N) return;
  int l = threadIdx.x & 63;
  int beg = off[node], end = off[node + 1];
  float ax = 0.f, ay = 0.f;
  int j = beg;
  for (; j + 1 < end; j += 2) {
    int2 p0 = pairs[j], p1 = pairs[j + 1];
    uint32 v0 = sup[(size_t)p0.x * 64 + l];
    uint32 v1 = sup[(size_t)p1.x * 64 + l];
    float w0 = __builtin_bit_cast(float, p0.y);
    float w1 = __builtin_bit_cast(float, p1.y);
    ax += __builtin_bit_cast(float, v0 << 16) * w0
        + __builtin_bit_cast(float, v1 << 16) * w1;
    ay += __builtin_bit_cast(float, v0 & 0xffff0000u) * w0
        + __builtin_bit_cast(float, v1 & 0xffff0000u) * w1;
  }
  if (j < end) {
    int2 p = pairs[j];
    uint32 v = sup[(size_t)p.x * 64 + l];
    float w = __builtin_bit_cast(float, p.y);
    ax += __builtin_bit_cast(float, v << 16) * w;
    ay += __builtin_bit_cast(float, v & 0xffff0000u) * w;
  }
  size_t o = (size_t)node * 64 + l;
  float2 v = io[o];
  v.x += ax; v.y += ay;
  if (resid) {
    float2 r = resid[o];
    v.x = (v.x + r.x) * 0.5f;
    v.y = (v.y + r.y) * 0.5f;
  }
  io[o] = v;
}

// ---------------- launch ----------------

extern "C" void kernel_launch(void* const* d_in, const int* in_sizes, int n_in,
                              void* d_out, int out_size, void* d_ws, size_t ws_size,
                              hipStream_t stream) {
  const float* x   = (const float*)d_in[0];
  const int*   ei  = (const int*)d_in[1];
  const float* ew  = (const float*)d_in[2];
  const float* W1  = (const float*)d_in[3];
  const float* Wl1 = (const float*)d_in[4];
  const float* b1  = (const float*)d_in[5];
  const float* W2  = (const float*)d_in[6];
  const float* Wl2 = (const float*)d_in[7];
  const float* b2  = (const float*)d_in[8];
  float* out = (float*)d_out;

  const int N = in_sizes[0] / D;
  const int E = in_sizes[1] / 2;
  const int* src = ei;
  const int* dst = ei + E;

  // workspace layout
  uint32* sup = (uint32*)d_ws;                   // N*64 uints (bf16 support, 25.6 MB)
  float* h1   = (float*)(sup + (size_t)N * 64);  // N*D floats (51.2 MB)
  short* BT1  = (short*)(h1 + (size_t)N * D);    // 2*D*D bf16 (64 KB)
  short* BT2  = BT1 + 2 * D * D;                 // 64 KB
  int* cnt    = (int*)(BT2 + 2 * D * D);         // N ints
  int* off    = cnt + N;                         // N+1 ints (+1 pad for alignment)
  int* csum   = off + (N + 2);                   // <=1024 ints
  int2* pairs = (int2*)(csum + SCAN_B);          // E int2 (12.8 MB), 8B-aligned

  const int nchunk = (N + SCAN_B - 1) / SCAN_B;

  // weight prep
  k_prepB<<<(2 * D * D + 255) / 256, 256, 0, stream>>>(W1, Wl1, BT1);
  k_prepB<<<(2 * D * D + 255) / 256, 256, 0, stream>>>(W2, Wl2, BT2);

  // CSR build (shared by both layers)
  k_zero<<<(N + 255) / 256, 256, 0, stream>>>(cnt, N);
  k_count<<<(E + 255) / 256, 256, 0, stream>>>(dst, cnt, E);
  k_scan1<<<nchunk, SCAN_B, 0, stream>>>(cnt, off, csum, N);
  k_scan2<<<1, SCAN_B, 0, stream>>>(csum, nchunk);
  k_scan3<<<nchunk, SCAN_B, 0, stream>>>(off, csum, N, E);
  k_zero<<<(N + 255) / 256, 256, 0, stream>>>(cnt, N);
  k_fill<<<(E + 255) / 256, 256, 0, stream>>>(src, dst, ew, off, cnt, pairs, E);

  const int mblocks = (N + BM - 1) / BM;
  const int ablocks = (N + 3) / 4;

  // layer 1: support = x@W1 ; h1 = x@Wloop1 + b1 ; h1 += agg
  k_gemm<<<mblocks, 256, 0, stream>>>(x, BT1, b1, (unsigned short*)sup, h1, N);
  k_agg<<<ablocks, 256, 0, stream>>>(sup, off, pairs, nullptr, (float2*)h1, N);

  // layer 2: support = h1@W2 ; out = h1@Wloop2 + b2 ; out = (x + out + agg)*0.5
  k_gemm<<<mblocks, 256, 0, stream>>>(h1, BT2, b2, (unsigned short*)sup, out, N);
  k_agg<<<ablocks, 256, 0, stream>>>(sup, off, pairs, (const float2*)x, (float2*)out, N);
}

// Round 3
// 449.328 us; speedup vs baseline: 1.3136x; 1.1113x over previous
//
#include <hip/hip_runtime.h>
#include <hip/hip_bf16.h>
#include <stdint.h>

#define D 128
#define BM 64
#define SCAN_B 1024

typedef __attribute__((ext_vector_type(8))) short bf16x8;
typedef __attribute__((ext_vector_type(4))) short short4_t;
typedef __attribute__((ext_vector_type(4))) float f32x4;
typedef unsigned int uint32;

static __device__ __forceinline__ short f2bf(float f) {
  uint32_t u = __builtin_bit_cast(uint32_t, f);
  u += 0x7fffu + ((u >> 16) & 1u);   // round-to-nearest-even
  return (short)(u >> 16);
}

// ---------------- CSR build ----------------

__global__ void k_zero(int* __restrict__ p, int n) {
  int i = blockIdx.x * blockDim.x + threadIdx.x;
  if (i < n) p[i] = 0;
}

__global__ void k_count(const int* __restrict__ dst, int* __restrict__ cnt, int E) {
  int e = blockIdx.x * blockDim.x + threadIdx.x;
  if (e < E) atomicAdd(&cnt[dst[e]], 1);
}

__global__ __launch_bounds__(SCAN_B) void k_scan1(const int* __restrict__ cnt,
                                                  int* __restrict__ off,
                                                  int* __restrict__ csum, int N) {
  __shared__ int s[SCAN_B];
  int t = threadIdx.x;
  int i = blockIdx.x * SCAN_B + t;
  int v = (i < N) ? cnt[i] : 0;
  s[t] = v;
  __syncthreads();
  for (int dd = 1; dd < SCAN_B; dd <<= 1) {
    int a = (t >= dd) ? s[t - dd] : 0;
    __syncthreads();
    s[t] += a;
    __syncthreads();
  }
  if (i < N) off[i] = s[t] - v;          // exclusive within chunk
  if (t == SCAN_B - 1) csum[blockIdx.x] = s[t];
}

__global__ __launch_bounds__(SCAN_B) void k_scan2(int* __restrict__ csum, int NC) {
  __shared__ int s[SCAN_B];
  int t = threadIdx.x;
  int v = (t < NC) ? csum[t] : 0;
  s[t] = v;
  __syncthreads();
  for (int dd = 1; dd < SCAN_B; dd <<= 1) {
    int a = (t >= dd) ? s[t - dd] : 0;
    __syncthreads();
    s[t] += a;
    __syncthreads();
  }
  if (t < NC) csum[t] = s[t] - v;        // exclusive chunk bases
}

__global__ __launch_bounds__(SCAN_B) void k_scan3(int* __restrict__ off,
                                                  const int* __restrict__ csum,
                                                  int N, int E) {
  int i = blockIdx.x * SCAN_B + threadIdx.x;
  if (i < N) off[i] += csum[blockIdx.x];
  if (i == 0) off[N] = E;
}

__global__ void k_fill(const int* __restrict__ src, const int* __restrict__ dst,
                       const float* __restrict__ wgt, const int* __restrict__ off,
                       int* __restrict__ cur, int2* __restrict__ pairs, int E) {
  int e = blockIdx.x * blockDim.x + threadIdx.x;
  if (e < E) {
    int dn = dst[e];
    int slot = atomicAdd(&cur[dn], 1);
    int p = off[dn] + slot;
    pairs[p] = make_int2(src[e], __builtin_bit_cast(int, wgt[e]));
  }
}

// ---------------- weight prep: BT[n][k] bf16, n in [0,256): [W | Wloop]^T ----------------

__global__ void k_prepB(const float* __restrict__ W, const float* __restrict__ Wl,
                        short* __restrict__ BT) {
  int idx = blockIdx.x * 256 + threadIdx.x;      // 2*D*D = 32768
  if (idx >= 2 * D * D) return;
  int n = idx >> 7, k = idx & (D - 1);
  float v = (n < D) ? W[k * D + n] : Wl[k * D + (n - D)];
  BT[idx] = f2bf(v);
}

// ---------------- fused GEMM: support(bf16) = A@W ; init(f32) = A@Wloop + b ----------------
// A fp32 [M][128]; BT bf16 [256][128] (cols 0..127 -> W, 128..255 -> Wloop)
// block = 256 threads (4 waves); tile BM=64 rows; wave w owns cols [w*64, w*64+64)

__global__ __launch_bounds__(256) void k_gemm(const float* __restrict__ A,
                                              const short* __restrict__ BT,
                                              const float* __restrict__ bias,
                                              unsigned short* __restrict__ support,
                                              float* __restrict__ init, int M) {
  __shared__ short As[BM * D];                   // 16 KB, XOR-swizzled
  const int t = threadIdx.x;
  const int l = t & 63;
  const int w = t >> 6;
  const int m0 = blockIdx.x * BM;

  // B fragments in registers: [cf][ks], col = w*64 + cf*16 + (l&15)
  bf16x8 bfrag[4][4];
  const int colbase = w * 64 + (l & 15);
#pragma unroll
  for (int cf = 0; cf < 4; ++cf) {
    const short* p = BT + (colbase + cf * 16) * D + (l >> 4) * 8;
#pragma unroll
    for (int ks = 0; ks < 4; ++ks) bfrag[cf][ks] = *(const bf16x8*)(p + ks * 32);
  }

  // stage A tile -> bf16 LDS (swizzled: short index ^= (row&7)<<3)
#pragma unroll
  for (int i = 0; i < 8; ++i) {
    int id = t + i * 256;                        // 0..2047
    int row = id >> 5, c4 = id & 31;
    int gr = m0 + row;
    float4 v;
    if (gr < M) v = *(const float4*)(A + (size_t)gr * D + c4 * 4);
    else { v.x = v.y = v.z = v.w = 0.f; }
    short4_t s4 = { f2bf(v.x), f2bf(v.y), f2bf(v.z), f2bf(v.w) };
    int sidx = row * D + ((c4 * 4) ^ ((row & 7) << 3));
    *(short4_t*)(As + sidx) = s4;
  }
  __syncthreads();

  f32x4 acc[4][4] = {};                          // [rf][cf]
#pragma unroll
  for (int ks = 0; ks < 4; ++ks) {
    bf16x8 afrag[4];
    int kcol = ks * 32 + (l >> 4) * 8;
#pragma unroll
    for (int rf = 0; rf < 4; ++rf) {
      int row = rf * 16 + (l & 15);
      afrag[rf] = *(const bf16x8*)(As + row * D + (kcol ^ ((row & 7) << 3)));
    }
#pragma unroll
    for (int rf = 0; rf < 4; ++rf)
#pragma unroll
      for (int cf = 0; cf < 4; ++cf)
        acc[rf][cf] = __builtin_amdgcn_mfma_f32_16x16x32_bf16(
            afrag[rf], bfrag[cf][ks], acc[rf][cf], 0, 0, 0);
  }

  // epilogue: waves 0,1 -> support (bf16) cols 0..127 ; waves 2,3 -> init (f32) + bias
  const bool isInit = (w >= 2);
#pragma unroll
  for (int cf = 0; cf < 4; ++cf) {
    int c = colbase + cf * 16;
    int oc = isInit ? (c - D) : c;
    float bv = isInit ? bias[oc] : 0.f;
#pragma unroll
    for (int rf = 0; rf < 4; ++rf) {
      int rbase = m0 + rf * 16 + (l >> 4) * 4;
#pragma unroll
      for (int j = 0; j < 4; ++j) {
        int r = rbase + j;
        if (r < M) {
          if (isInit) init[(size_t)r * D + oc] = acc[rf][cf][j] + bv;
          else        support[(size_t)r * D + oc] = (unsigned short)f2bf(acc[rf][cf][j]);
        }
      }
    }
  }
}

// ---------------- aggregation: io[n] += sum_j bf16(support[src_j])*w_j (opt residual) ----------------
// one wave per node; lane l handles channels 2l, 2l+1 (one uint = 2 bf16).
// 8-edge batches, pair loads software-pipelined one batch ahead; masked tail
// entries use clamped index + zero weight so all loads stay unconditional.

__global__ __launch_bounds__(256) void k_agg(const uint32* __restrict__ sup,
                                             const int* __restrict__ off,
                                             const int2* __restrict__ pairs,
                                             const float2* __restrict__ resid,
                                             float2* __restrict__ io, int N) {
  int node = blockIdx.x * 4 + (threadIdx.x >> 6);
  if (node >= N) return;
  int l = threadIdx.x & 63;
  int beg = off[node], end = off[node + 1];
  float ax = 0.f, ay = 0.f;
  int nb = (end - beg + 7) >> 3;                 // number of 8-edge batches

  if (nb > 0) {
    int2 p[8];
#pragma unroll
    for (int i = 0; i < 8; ++i) {
      int jj = beg + i;
      int2 tt = pairs[jj < end ? jj : beg];
      if (jj >= end) tt.y = 0;
      p[i] = tt;
    }
    int j = beg + 8;
    for (int b = 1; b < nb; ++b, j += 8) {
      int2 pn[8];
#pragma unroll
      for (int i = 0; i < 8; ++i) {              // prefetch next batch's pairs
        int jj = j + i;
        int2 tt = pairs[jj < end ? jj : beg];
        if (jj >= end) tt.y = 0;
        pn[i] = tt;
      }
      uint32 v[8];
#pragma unroll
      for (int i = 0; i < 8; ++i) v[i] = sup[(size_t)p[i].x * 64 + l];
#pragma unroll
      for (int i = 0; i < 8; ++i) {
        float w = __builtin_bit_cast(float, p[i].y);
        ax = fmaf(__builtin_bit_cast(float, v[i] << 16), w, ax);
        ay = fmaf(__builtin_bit_cast(float, v[i] & 0xffff0000u), w, ay);
      }
#pragma unroll
      for (int i = 0; i < 8; ++i) p[i] = pn[i];
    }
    // last (possibly masked) batch
    uint32 v[8];
#pragma unroll
    for (int i = 0; i < 8; ++i) v[i] = sup[(size_t)p[i].x * 64 + l];
#pragma unroll
    for (int i = 0; i < 8; ++i) {
      float w = __builtin_bit_cast(float, p[i].y);
      ax = fmaf(__builtin_bit_cast(float, v[i] << 16), w, ax);
      ay = fmaf(__builtin_bit_cast(float, v[i] & 0xffff0000u), w, ay);
    }
  }

  size_t o = (size_t)node * 64 + l;
  float2 v = io[o];
  v.x += ax; v.y += ay;
  if (resid) {
    float2 r = resid[o];
    v.x = (v.x + r.x) * 0.5f;
    v.y = (v.y + r.y) * 0.5f;
  }
  io[o] = v;
}

// ---------------- launch ----------------

extern "C" void kernel_launch(void* const* d_in, const int* in_sizes, int n_in,
                              void* d_out, int out_size, void* d_ws, size_t ws_size,
                              hipStream_t stream) {
  const float* x   = (const float*)d_in[0];
  const int*   ei  = (const int*)d_in[1];
  const float* ew  = (const float*)d_in[2];
  const float* W1  = (const float*)d_in[3];
  const float* Wl1 = (const float*)d_in[4];
  const float* b1  = (const float*)d_in[5];
  const float* W2  = (const float*)d_in[6];
  const float* Wl2 = (const float*)d_in[7];
  const float* b2  = (const float*)d_in[8];
  float* out = (float*)d_out;

  const int N = in_sizes[0] / D;
  const int E = in_sizes[1] / 2;
  const int* src = ei;
  const int* dst = ei + E;

  // workspace layout
  uint32* sup = (uint32*)d_ws;                   // N*64 uints (bf16 support, 25.6 MB)
  float* h1   = (float*)(sup + (size_t)N * 64);  // N*D floats (51.2 MB)
  short* BT1  = (short*)(h1 + (size_t)N * D);    // 2*D*D bf16 (64 KB)
  short* BT2  = BT1 + 2 * D * D;                 // 64 KB
  int* cnt    = (int*)(BT2 + 2 * D * D);         // N ints
  int* off    = cnt + N;                         // N+1 ints (+1 pad for alignment)
  int* csum   = off + (N + 2);                   // <=1024 ints
  int2* pairs = (int2*)(csum + SCAN_B);          // E int2 (12.8 MB), 8B-aligned

  const int nchunk = (N + SCAN_B - 1) / SCAN_B;

  // weight prep
  k_prepB<<<(2 * D * D + 255) / 256, 256, 0, stream>>>(W1, Wl1, BT1);
  k_prepB<<<(2 * D * D + 255) / 256, 256, 0, stream>>>(W2, Wl2, BT2);

  // CSR build (shared by both layers)
  k_zero<<<(N + 255) / 256, 256, 0, stream>>>(cnt, N);
  k_count<<<(E + 255) / 256, 256, 0, stream>>>(dst, cnt, E);
  k_scan1<<<nchunk, SCAN_B, 0, stream>>>(cnt, off, csum, N);
  k_scan2<<<1, SCAN_B, 0, stream>>>(csum, nchunk);
  k_scan3<<<nchunk, SCAN_B, 0, stream>>>(off, csum, N, E);
  k_zero<<<(N + 255) / 256, 256, 0, stream>>>(cnt, N);
  k_fill<<<(E + 255) / 256, 256, 0, stream>>>(src, dst, ew, off, cnt, pairs, E);

  const int mblocks = (N + BM - 1) / BM;
  const int ablocks = (N + 3) / 4;

  // layer 1: support = x@W1 ; h1 = x@Wloop1 + b1 ; h1 += agg
  k_gemm<<<mblocks, 256, 0, stream>>>(x, BT1, b1, (unsigned short*)sup, h1, N);
  k_agg<<<ablocks, 256, 0, stream>>>(sup, off, pairs, nullptr, (float2*)h1, N);

  // layer 2: support = h1@W2 ; out = h1@Wloop2 + b2 ; out = (x + out + agg)*0.5
  k_gemm<<<mblocks, 256, 0, stream>>>(h1, BT2, b2, (unsigned short*)sup, out, N);
  k_agg<<<ablocks, 256, 0, stream>>>(sup, off, pairs, (const float2*)x, (float2*)out, N);
}

// Round 4
// 367.224 us; speedup vs baseline: 1.6072x; 1.2236x over previous
//
#include <hip/hip_runtime.h>
#include <hip/hip_bf16.h>
#include <stdint.h>

#define D 128
#define BM 64
#define NB_BITS 10            // 1024 nodes per bucket
#define BCAP 20480            // max edges per bucket (mean 16384, sigma ~128)
#define C3_EPB 4096           // edges per k_bucket block

typedef __attribute__((ext_vector_type(8))) short bf16x8;
typedef __attribute__((ext_vector_type(4))) short short4_t;
typedef __attribute__((ext_vector_type(4))) float f32x4;
typedef unsigned int uint32;

static __device__ __forceinline__ short f2bf(float f) {
  uint32_t u = __builtin_bit_cast(uint32_t, f);
  u += 0x7fffu + ((u >> 16) & 1u);   // round-to-nearest-even
  return (short)(u >> 16);
}

// ---------------- tiny zero ----------------

__global__ void k_zero(int* __restrict__ p, int n) {
  int i = blockIdx.x * blockDim.x + threadIdx.x;
  if (i < n) p[i] = 0;
}

// ---------------- pass 1: bucket-group edges into 16B records ----------------
// block = 256 thr, C3_EPB edges. LDS histogram over nb (<=256) buckets, one
// global atomicAdd per (block,bucket) to reserve a contiguous run, then
// scatter records in runs (~21 contiguous records) -> L2 write-combines.

__global__ __launch_bounds__(256) void k_bucket(const int* __restrict__ src,
                                                const int* __restrict__ dst,
                                                const float* __restrict__ wgt,
                                                int* __restrict__ bcur,
                                                int4* __restrict__ rec,
                                                int E, int nb) {
  __shared__ int lhist[256];
  __shared__ int lbase[256];
  const int t = threadIdx.x;
  const int e0 = blockIdx.x * C3_EPB;
  if (t < nb) lhist[t] = 0;
  __syncthreads();
  for (int i = t; i < C3_EPB; i += 256) {
    int e = e0 + i;
    if (e < E) atomicAdd(&lhist[dst[e] >> NB_BITS], 1);
  }
  __syncthreads();
  if (t < nb) {
    lbase[t] = atomicAdd(&bcur[t], lhist[t]);
    lhist[t] = 0;                       // becomes local rank cursor
  }
  __syncthreads();
  for (int i = t; i < C3_EPB; i += 256) {
    int e = e0 + i;
    if (e < E) {
      int d = dst[e];
      int b = d >> NB_BITS;
      int r = lbase[b] + atomicAdd(&lhist[b], 1);
      if (r >= BCAP) r = BCAP - 1;      // defensive clamp (statistically unreachable)
      rec[(size_t)b * BCAP + r] =
          make_int4(src[e], __builtin_bit_cast(int, wgt[e]), d, 0);
    }
  }
}

// ---------------- pass 2: per-bucket LDS counting sort -> off[] + pairs[] ----------------
// one block per bucket; all random writes confined to the bucket's private
// ~131KB pairs window; zero global atomics.

__global__ __launch_bounds__(256) void k_sort(const int4* __restrict__ rec,
                                              const int* __restrict__ bcur,
                                              int* __restrict__ off,
                                              int2* __restrict__ pairs,
                                              int N, int E, int nb) {
  __shared__ int bc[256];
  __shared__ int psum[256];
  __shared__ int lofs[1 << NB_BITS];
  const int t = threadIdx.x;
  const int b = blockIdx.x;

  // scan bucket counts (all blocks redundantly; 256-wide Hillis-Steele)
  int mycnt = (t < nb) ? min(bcur[t], BCAP) : 0;
  bc[t] = mycnt;
  __syncthreads();
  for (int dd = 1; dd < 256; dd <<= 1) {
    int a = (t >= dd) ? bc[t - dd] : 0;
    __syncthreads();
    bc[t] += a;
    __syncthreads();
  }
  const int cntb = min(bcur[b], BCAP);
  const int ebase = bc[b] - cntb;          // exclusive scan value for bucket b
  const int total = bc[nb - 1];
  const size_t rbase = (size_t)b * BCAP;
  const int n0 = b << NB_BITS;
  const int nn = min(1 << NB_BITS, N - n0);

  // local histogram over the bucket's nodes
  for (int i = t; i < (1 << NB_BITS); i += 256) lofs[i] = 0;
  __syncthreads();
  for (int i = t; i < cntb; i += 256)
    atomicAdd(&lofs[rec[rbase + i].z & ((1 << NB_BITS) - 1)], 1);
  __syncthreads();

  // exclusive scan of 1024 counts: 4 per thread + 256-wide scan of partials
  int v0 = lofs[4 * t], v1 = lofs[4 * t + 1], v2 = lofs[4 * t + 2], v3 = lofs[4 * t + 3];
  int sum = v0 + v1 + v2 + v3;
  psum[t] = sum;
  __syncthreads();
  for (int dd = 1; dd < 256; dd <<= 1) {
    int a = (t >= dd) ? psum[t - dd] : 0;
    __syncthreads();
    psum[t] += a;
    __syncthreads();
  }
  int run = psum[t] - sum;
  lofs[4 * t] = run; run += v0;
  lofs[4 * t + 1] = run; run += v1;
  lofs[4 * t + 2] = run; run += v2;
  lofs[4 * t + 3] = run;
  __syncthreads();

  // emit per-node offsets
  for (int i = t; i < nn; i += 256) off[n0 + i] = ebase + lofs[i];
  if (b == nb - 1 && t == 0) off[N] = total;

  // scatter into final sorted order (lofs doubles as cursor array)
  for (int i = t; i < cntb; i += 256) {
    int4 rr = rec[rbase + i];
    int r = atomicAdd(&lofs[rr.z & ((1 << NB_BITS) - 1)], 1);
    pairs[ebase + r] = make_int2(rr.x, rr.y);
  }
}

// ---------------- weight prep: BT[n][k] bf16, n in [0,256): [W | Wloop]^T ----------------

__global__ void k_prepB(const float* __restrict__ W, const float* __restrict__ Wl,
                        short* __restrict__ BT) {
  int idx = blockIdx.x * 256 + threadIdx.x;      // 2*D*D = 32768
  if (idx >= 2 * D * D) return;
  int n = idx >> 7, k = idx & (D - 1);
  float v = (n < D) ? W[k * D + n] : Wl[k * D + (n - D)];
  BT[idx] = f2bf(v);
}

// ---------------- fused GEMM: support(bf16) = A@W ; init(f32) = A@Wloop + b ----------------

__global__ __launch_bounds__(256) void k_gemm(const float* __restrict__ A,
                                              const short* __restrict__ BT,
                                              const float* __restrict__ bias,
                                              unsigned short* __restrict__ support,
                                              float* __restrict__ init, int M) {
  __shared__ short As[BM * D];                   // 16 KB, XOR-swizzled
  const int t = threadIdx.x;
  const int l = t & 63;
  const int w = t >> 6;
  const int m0 = blockIdx.x * BM;

  bf16x8 bfrag[4][4];
  const int colbase = w * 64 + (l & 15);
#pragma unroll
  for (int cf = 0; cf < 4; ++cf) {
    const short* p = BT + (colbase + cf * 16) * D + (l >> 4) * 8;
#pragma unroll
    for (int ks = 0; ks < 4; ++ks) bfrag[cf][ks] = *(const bf16x8*)(p + ks * 32);
  }

#pragma unroll
  for (int i = 0; i < 8; ++i) {
    int id = t + i * 256;                        // 0..2047
    int row = id >> 5, c4 = id & 31;
    int gr = m0 + row;
    float4 v;
    if (gr < M) v = *(const float4*)(A + (size_t)gr * D + c4 * 4);
    else { v.x = v.y = v.z = v.w = 0.f; }
    short4_t s4 = { f2bf(v.x), f2bf(v.y), f2bf(v.z), f2bf(v.w) };
    int sidx = row * D + ((c4 * 4) ^ ((row & 7) << 3));
    *(short4_t*)(As + sidx) = s4;
  }
  __syncthreads();

  f32x4 acc[4][4] = {};                          // [rf][cf]
#pragma unroll
  for (int ks = 0; ks < 4; ++ks) {
    bf16x8 afrag[4];
    int kcol = ks * 32 + (l >> 4) * 8;
#pragma unroll
    for (int rf = 0; rf < 4; ++rf) {
      int row = rf * 16 + (l & 15);
      afrag[rf] = *(const bf16x8*)(As + row * D + (kcol ^ ((row & 7) << 3)));
    }
#pragma unroll
    for (int rf = 0; rf < 4; ++rf)
#pragma unroll
      for (int cf = 0; cf < 4; ++cf)
        acc[rf][cf] = __builtin_amdgcn_mfma_f32_16x16x32_bf16(
            afrag[rf], bfrag[cf][ks], acc[rf][cf], 0, 0, 0);
  }

  const bool isInit = (w >= 2);
#pragma unroll
  for (int cf = 0; cf < 4; ++cf) {
    int c = colbase + cf * 16;
    int oc = isInit ? (c - D) : c;
    float bv = isInit ? bias[oc] : 0.f;
#pragma unroll
    for (int rf = 0; rf < 4; ++rf) {
      int rbase = m0 + rf * 16 + (l >> 4) * 4;
#pragma unroll
      for (int j = 0; j < 4; ++j) {
        int r = rbase + j;
        if (r < M) {
          if (isInit) init[(size_t)r * D + oc] = acc[rf][cf][j] + bv;
          else        support[(size_t)r * D + oc] = (unsigned short)f2bf(acc[rf][cf][j]);
        }
      }
    }
  }
}

// ---------------- aggregation: io[n] += sum_j bf16(support[src_j])*w_j (opt residual) ----------------
// one wave per node; lane l handles channels 2l, 2l+1 (one uint = 2 bf16).
// 8-edge batches, pair loads software-pipelined one batch ahead.

__global__ __launch_bounds__(256) void k_agg(const uint32* __restrict__ sup,
                                             const int* __restrict__ off,
                                             const int2* __restrict__ pairs,
                                             const float2* __restrict__ resid,
                                             float2* __restrict__ io, int N) {
  int node = blockIdx.x * 4 + (threadIdx.x >> 6);
  if (node >= N) return;
  int l = threadIdx.x & 63;
  int beg = off[node], end = off[node + 1];
  float ax = 0.f, ay = 0.f;
  int nb = (end - beg + 7) >> 3;                 // number of 8-edge batches

  if (nb > 0) {
    int2 p[8];
#pragma unroll
    for (int i = 0; i < 8; ++i) {
      int jj = beg + i;
      int2 tt = pairs[jj < end ? jj : beg];
      if (jj >= end) tt.y = 0;
      p[i] = tt;
    }
    int j = beg + 8;
    for (int b = 1; b < nb; ++b, j += 8) {
      int2 pn[8];
#pragma unroll
      for (int i = 0; i < 8; ++i) {              // prefetch next batch's pairs
        int jj = j + i;
        int2 tt = pairs[jj < end ? jj : beg];
        if (jj >= end) tt.y = 0;
        pn[i] = tt;
      }
      uint32 v[8];
#pragma unroll
      for (int i = 0; i < 8; ++i) v[i] = sup[(size_t)p[i].x * 64 + l];
#pragma unroll
      for (int i = 0; i < 8; ++i) {
        float w = __builtin_bit_cast(float, p[i].y);
        ax = fmaf(__builtin_bit_cast(float, v[i] << 16), w, ax);
        ay = fmaf(__builtin_bit_cast(float, v[i] & 0xffff0000u), w, ay);
      }
#pragma unroll
      for (int i = 0; i < 8; ++i) p[i] = pn[i];
    }
    uint32 v[8];
#pragma unroll
    for (int i = 0; i < 8; ++i) v[i] = sup[(size_t)p[i].x * 64 + l];
#pragma unroll
    for (int i = 0; i < 8; ++i) {
      float w = __builtin_bit_cast(float, p[i].y);
      ax = fmaf(__builtin_bit_cast(float, v[i] << 16), w, ax);
      ay = fmaf(__builtin_bit_cast(float, v[i] & 0xffff0000u), w, ay);
    }
  }

  size_t o = (size_t)node * 64 + l;
  float2 v = io[o];
  v.x += ax; v.y += ay;
  if (resid) {
    float2 r = resid[o];
    v.x = (v.x + r.x) * 0.5f;
    v.y = (v.y + r.y) * 0.5f;
  }
  io[o] = v;
}

// ---------------- launch ----------------

extern "C" void kernel_launch(void* const* d_in, const int* in_sizes, int n_in,
                              void* d_out, int out_size, void* d_ws, size_t ws_size,
                              hipStream_t stream) {
  const float* x   = (const float*)d_in[0];
  const int*   ei  = (const int*)d_in[1];
  const float* ew  = (const float*)d_in[2];
  const float* W1  = (const float*)d_in[3];
  const float* Wl1 = (const float*)d_in[4];
  const float* b1  = (const float*)d_in[5];
  const float* W2  = (const float*)d_in[6];
  const float* Wl2 = (const float*)d_in[7];
  const float* b2  = (const float*)d_in[8];
  float* out = (float*)d_out;

  const int N = in_sizes[0] / D;
  const int E = in_sizes[1] / 2;
  const int* src = ei;
  const int* dst = ei + E;
  const int nb = (N + (1 << NB_BITS) - 1) >> NB_BITS;   // 98 buckets

  // workspace layout (~90 MB)
  uint32* sup = (uint32*)d_ws;                   // N*64 uints (bf16 support, 25.6 MB)
  float* h1   = (float*)(sup + (size_t)N * 64);  // N*D floats (51.2 MB)
  int4* rec   = (int4*)h1;                       // ALIAS: nb*BCAP int4 (32.1 MB) — dead before gemm1 writes h1
  short* BT1  = (short*)(h1 + (size_t)N * D);    // 2*D*D bf16 (64 KB)
  short* BT2  = BT1 + 2 * D * D;                 // 64 KB
  int* off    = (int*)(BT2 + 2 * D * D);         // N+2 ints
  int* bcur   = off + (N + 2);                   // 256 ints
  int2* pairs = (int2*)(bcur + 256);             // E int2 (12.8 MB), 8B-aligned

  // weight prep
  k_prepB<<<(2 * D * D + 255) / 256, 256, 0, stream>>>(W1, Wl1, BT1);
  k_prepB<<<(2 * D * D + 255) / 256, 256, 0, stream>>>(W2, Wl2, BT2);

  // CSR build via two-level bucket sort
  k_zero<<<1, 256, 0, stream>>>(bcur, 256);
  k_bucket<<<(E + C3_EPB - 1) / C3_EPB, 256, 0, stream>>>(src, dst, ew, bcur, rec, E, nb);
  k_sort<<<nb, 256, 0, stream>>>(rec, bcur, off, pairs, N, E, nb);

  const int mblocks = (N + BM - 1) / BM;
  const int ablocks = (N + 3) / 4;

  // layer 1: support = x@W1 ; h1 = x@Wloop1 + b1 ; h1 += agg   (rec dead from here)
  k_gemm<<<mblocks, 256, 0, stream>>>(x, BT1, b1, (unsigned short*)sup, h1, N);
  k_agg<<<ablocks, 256, 0, stream>>>(sup, off, pairs, nullptr, (float2*)h1, N);

  // layer 2: support = h1@W2 ; out = h1@Wloop2 + b2 ; out = (x + out + agg)*0.5
  k_gemm<<<mblocks, 256, 0, stream>>>(h1, BT2, b2, (unsigned short*)sup, out, N);
  k_agg<<<ablocks, 256, 0, stream>>>(sup, off, pairs, (const float2*)x, (float2*)out, N);
}

// Round 5
// 345.657 us; speedup vs baseline: 1.7075x; 1.0624x over previous
//
#include <hip/hip_runtime.h>
#include <hip/hip_bf16.h>
#include <stdint.h>

#define D 128
#define BM 64
#define NB_BITS 9             // 512 nodes per bucket
#define NPB (1 << NB_BITS)
#define BCAP 10240            // max edges/bucket (mean 8163)
#define C3_EPB 4096           // edges per k_bucket block

typedef __attribute__((ext_vector_type(8))) short bf16x8;
typedef __attribute__((ext_vector_type(4))) short short4_t;
typedef __attribute__((ext_vector_type(4))) float f32x4;
typedef unsigned int uint32;

static __device__ __forceinline__ short f2bf(float f) {
  uint32_t u = __builtin_bit_cast(uint32_t, f);
  u += 0x7fffu + ((u >> 16) & 1u);   // round-to-nearest-even
  return (short)(u >> 16);
}

// ---------------- prep: BT1,BT2 bf16 [256][128] = [W|Wloop]^T ; zero bcur ----------------

__global__ void k_prep(const float* __restrict__ W1, const float* __restrict__ Wl1,
                       const float* __restrict__ W2, const float* __restrict__ Wl2,
                       short* __restrict__ BT1, short* __restrict__ BT2,
                       int* __restrict__ bcur) {
  int idx = blockIdx.x * 256 + threadIdx.x;
  if (idx < 2 * D * D) {
    int n = idx >> 7, k = idx & (D - 1);
    float v = (n < D) ? W1[k * D + n] : Wl1[k * D + (n - D)];
    BT1[idx] = f2bf(v);
  } else if (idx < 4 * D * D) {
    int i2 = idx - 2 * D * D;
    int n = i2 >> 7, k = i2 & (D - 1);
    float v = (n < D) ? W2[k * D + n] : Wl2[k * D + (n - D)];
    BT2[i2] = f2bf(v);
  } else if (idx < 4 * D * D + 256) {
    bcur[idx - 4 * D * D] = 0;
  }
}

// ---------------- pass 1: bucket-group edges into 16B records ----------------

__global__ __launch_bounds__(256) void k_bucket(const int* __restrict__ src,
                                                const int* __restrict__ dst,
                                                const float* __restrict__ wgt,
                                                int* __restrict__ bcur,
                                                int4* __restrict__ rec,
                                                int E, int nb) {
  __shared__ int lhist[256];
  __shared__ int lbase[256];
  const int t = threadIdx.x;
  const int e0 = blockIdx.x * C3_EPB;
  if (t < nb) lhist[t] = 0;
  __syncthreads();
  for (int i = t; i < C3_EPB; i += 256) {
    int e = e0 + i;
    if (e < E) atomicAdd(&lhist[dst[e] >> NB_BITS], 1);
  }
  __syncthreads();
  if (t < nb) {
    lbase[t] = atomicAdd(&bcur[t], lhist[t]);
    lhist[t] = 0;                       // becomes local rank cursor
  }
  __syncthreads();
  for (int i = t; i < C3_EPB; i += 256) {
    int e = e0 + i;
    if (e < E) {
      int d = dst[e];
      int b = d >> NB_BITS;
      int r = lbase[b] + atomicAdd(&lhist[b], 1);
      if (r >= BCAP) r = BCAP - 1;      // defensive clamp (statistically unreachable)
      rec[(size_t)b * BCAP + r] =
          make_int4(src[e], __builtin_bit_cast(int, wgt[e]), d, 0);
    }
  }
}

// ---------------- pass 2: per-bucket LDS counting sort -> off[] + pairs[] ----------------

__global__ __launch_bounds__(256) void k_sort(const int4* __restrict__ rec,
                                              const int* __restrict__ bcur,
                                              int* __restrict__ off,
                                              int2* __restrict__ pairs,
                                              int N, int nb) {
  __shared__ int bc[256];
  __shared__ int psum[256];
  __shared__ int lofs[NPB];
  const int t = threadIdx.x;
  const int b = blockIdx.x;

  // scan bucket counts (redundant per block; 256-wide Hillis-Steele)
  int mycnt = (t < nb) ? min(bcur[t], BCAP) : 0;
  bc[t] = mycnt;
  __syncthreads();
  for (int dd = 1; dd < 256; dd <<= 1) {
    int a = (t >= dd) ? bc[t - dd] : 0;
    __syncthreads();
    bc[t] += a;
    __syncthreads();
  }
  const int cntb = min(bcur[b], BCAP);
  const int ebase = bc[b] - cntb;
  const int total = bc[nb - 1];
  const size_t rbase = (size_t)b * BCAP;
  const int n0 = b << NB_BITS;
  const int nn = min(NPB, N - n0);

  // local histogram over the bucket's nodes
  for (int i = t; i < NPB; i += 256) lofs[i] = 0;
  __syncthreads();
  for (int i = t; i < cntb; i += 256)
    atomicAdd(&lofs[rec[rbase + i].z & (NPB - 1)], 1);
  __syncthreads();

  // exclusive scan of 512 counts: 2/thread + 256-wide scan of partials
  int v0 = lofs[2 * t], v1 = lofs[2 * t + 1];
  int sum = v0 + v1;
  psum[t] = sum;
  __syncthreads();
  for (int dd = 1; dd < 256; dd <<= 1) {
    int a = (t >= dd) ? psum[t - dd] : 0;
    __syncthreads();
    psum[t] += a;
    __syncthreads();
  }
  int run = psum[t] - sum;
  lofs[2 * t] = run;
  lofs[2 * t + 1] = run + v0;
  __syncthreads();

  // emit per-node offsets
  for (int i = t; i < nn; i += 256) off[n0 + i] = ebase + lofs[i];
  if (b == nb - 1 && t == 0) off[N] = total;
  __syncthreads();                      // off-emit must finish before lofs is mutated

  // scatter into final sorted order (lofs doubles as cursor array)
  for (int i = t; i < cntb; i += 256) {
    int4 rr = rec[rbase + i];
    int r = atomicAdd(&lofs[rr.z & (NPB - 1)], 1);
    pairs[ebase + r] = make_int2(rr.x, rr.y);
  }
}

// ---------------- fused GEMM: support(bf16) = A@W ; init = A@Wloop + b [+resid, *0.5] ----------------
// ABF16: A stored bf16 (no conversion in staging). IBF16: init written bf16.
// RESID: init = (acc + bias + resid)*0.5  (layer-2 residual fold)

template<bool ABF16, bool IBF16, bool RESID>
__global__ __launch_bounds__(256) void k_gemm(const void* __restrict__ Ap,
                                              const short* __restrict__ BT,
                                              const float* __restrict__ bias,
                                              const float* __restrict__ resid,
                                              unsigned short* __restrict__ support,
                                              void* __restrict__ initp, int M) {
  __shared__ short As[BM * D];                   // 16 KB, XOR-swizzled
  const int t = threadIdx.x;
  const int l = t & 63;
  const int w = t >> 6;
  const int m0 = blockIdx.x * BM;

  bf16x8 bfrag[4][4];
  const int colbase = w * 64 + (l & 15);
#pragma unroll
  for (int cf = 0; cf < 4; ++cf) {
    const short* p = BT + (colbase + cf * 16) * D + (l >> 4) * 8;
#pragma unroll
    for (int ks = 0; ks < 4; ++ks) bfrag[cf][ks] = *(const bf16x8*)(p + ks * 32);
  }

#pragma unroll
  for (int i = 0; i < 8; ++i) {
    int id = t + i * 256;                        // 0..2047
    int row = id >> 5, c4 = id & 31;
    int gr = m0 + row;
    short4_t s4;
    if (ABF16) {
      if (gr < M) s4 = *(const short4_t*)((const short*)Ap + (size_t)gr * D + c4 * 4);
      else { s4[0] = s4[1] = s4[2] = s4[3] = 0; }
    } else {
      float4 v;
      if (gr < M) v = *(const float4*)((const float*)Ap + (size_t)gr * D + c4 * 4);
      else { v.x = v.y = v.z = v.w = 0.f; }
      s4[0] = f2bf(v.x); s4[1] = f2bf(v.y); s4[2] = f2bf(v.z); s4[3] = f2bf(v.w);
    }
    int sidx = row * D + ((c4 * 4) ^ ((row & 7) << 3));
    *(short4_t*)(As + sidx) = s4;
  }
  __syncthreads();

  f32x4 acc[4][4] = {};                          // [rf][cf]
#pragma unroll
  for (int ks = 0; ks < 4; ++ks) {
    bf16x8 afrag[4];
    int kcol = ks * 32 + (l >> 4) * 8;
#pragma unroll
    for (int rf = 0; rf < 4; ++rf) {
      int row = rf * 16 + (l & 15);
      afrag[rf] = *(const bf16x8*)(As + row * D + (kcol ^ ((row & 7) << 3)));
    }
#pragma unroll
    for (int rf = 0; rf < 4; ++rf)
#pragma unroll
      for (int cf = 0; cf < 4; ++cf)
        acc[rf][cf] = __builtin_amdgcn_mfma_f32_16x16x32_bf16(
            afrag[rf], bfrag[cf][ks], acc[rf][cf], 0, 0, 0);
  }

  // epilogue: waves 0,1 -> support (bf16); waves 2,3 -> init (+bias [+resid]*0.5)
  const bool isInit = (w >= 2);
#pragma unroll
  for (int cf = 0; cf < 4; ++cf) {
    int c = colbase + cf * 16;
    int oc = isInit ? (c - D) : c;
    float bv = isInit ? bias[oc] : 0.f;
#pragma unroll
    for (int rf = 0; rf < 4; ++rf) {
      int rbase = m0 + rf * 16 + (l >> 4) * 4;
#pragma unroll
      for (int j = 0; j < 4; ++j) {
        int r = rbase + j;
        if (r < M) {
          if (isInit) {
            float val = acc[rf][cf][j] + bv;
            if (RESID) val = (val + resid[(size_t)r * D + oc]) * 0.5f;
            if (IBF16) ((unsigned short*)initp)[(size_t)r * D + oc] = (unsigned short)f2bf(val);
            else       ((float*)initp)[(size_t)r * D + oc] = val;
          } else {
            support[(size_t)r * D + oc] = (unsigned short)f2bf(acc[rf][cf][j]);
          }
        }
      }
    }
  }
}

// ---------------- aggregation: io[n] += [0.5*] sum_j bf16(support[src_j])*w_j ----------------
// MODE 0: io bf16 (uint32 = 2ch), scale 1.  MODE 1: io f32 (float2), scale 0.5.
// one wave per node; 8-edge batches, pair loads pipelined one batch ahead.

template<int MODE>
__global__ __launch_bounds__(256) void k_agg(const uint32* __restrict__ sup,
                                             const int* __restrict__ off,
                                             const int2* __restrict__ pairs,
                                             void* __restrict__ iop, int N) {
  int node = blockIdx.x * 4 + (threadIdx.x >> 6);
  if (node >= N) return;
  int l = threadIdx.x & 63;
  int beg = off[node], end = off[node + 1];
  float ax = 0.f, ay = 0.f;
  int nbt = (end - beg + 7) >> 3;

  if (nbt > 0) {
    int2 p[8];
#pragma unroll
    for (int i = 0; i < 8; ++i) {
      int jj = beg + i;
      int2 tt = pairs[jj < end ? jj : beg];
      if (jj >= end) tt.y = 0;
      p[i] = tt;
    }
    int j = beg + 8;
    for (int b = 1; b < nbt; ++b, j += 8) {
      int2 pn[8];
#pragma unroll
      for (int i = 0; i < 8; ++i) {              // prefetch next batch's pairs
        int jj = j + i;
        int2 tt = pairs[jj < end ? jj : beg];
        if (jj >= end) tt.y = 0;
        pn[i] = tt;
      }
      uint32 v[8];
#pragma unroll
      for (int i = 0; i < 8; ++i) v[i] = sup[(size_t)p[i].x * 64 + l];
#pragma unroll
      for (int i = 0; i < 8; ++i) {
        float w = __builtin_bit_cast(float, p[i].y);
        ax = fmaf(__builtin_bit_cast(float, v[i] << 16), w, ax);
        ay = fmaf(__builtin_bit_cast(float, v[i] & 0xffff0000u), w, ay);
      }
#pragma unroll
      for (int i = 0; i < 8; ++i) p[i] = pn[i];
    }
    uint32 v[8];
#pragma unroll
    for (int i = 0; i < 8; ++i) v[i] = sup[(size_t)p[i].x * 64 + l];
#pragma unroll
    for (int i = 0; i < 8; ++i) {
      float w = __builtin_bit_cast(float, p[i].y);
      ax = fmaf(__builtin_bit_cast(float, v[i] << 16), w, ax);
      ay = fmaf(__builtin_bit_cast(float, v[i] & 0xffff0000u), w, ay);
    }
  }

  size_t o = (size_t)node * 64 + l;
  if (MODE == 0) {
    uint32* io = (uint32*)iop;
    uint32 cur = io[o];
    float vx = __builtin_bit_cast(float, cur << 16) + ax;
    float vy = __builtin_bit_cast(float, cur & 0xffff0000u) + ay;
    io[o] = ((uint32)(unsigned short)f2bf(vy) << 16) | (unsigned short)f2bf(vx);
  } else {
    float2* io = (float2*)iop;
    float2 v = io[o];
    v.x = fmaf(0.5f, ax, v.x);
    v.y = fmaf(0.5f, ay, v.y);
    io[o] = v;
  }
}

// ---------------- launch ----------------

extern "C" void kernel_launch(void* const* d_in, const int* in_sizes, int n_in,
                              void* d_out, int out_size, void* d_ws, size_t ws_size,
                              hipStream_t stream) {
  const float* x   = (const float*)d_in[0];
  const int*   ei  = (const int*)d_in[1];
  const float* ew  = (const float*)d_in[2];
  const float* W1  = (const float*)d_in[3];
  const float* Wl1 = (const float*)d_in[4];
  const float* b1  = (const float*)d_in[5];
  const float* W2  = (const float*)d_in[6];
  const float* Wl2 = (const float*)d_in[7];
  const float* b2  = (const float*)d_in[8];
  float* out = (float*)d_out;

  const int N = in_sizes[0] / D;
  const int E = in_sizes[1] / 2;
  const int* src = ei;
  const int* dst = ei + E;
  const int nbuck = (N + NPB - 1) >> NB_BITS;           // 196

  // workspace layout (~96 MB)
  uint32* sup = (uint32*)d_ws;                   // N*64 u32 (bf16 support, 25.6 MB)
  uint32* h1b = sup + (size_t)N * 64;            // N*64 u32 (bf16 h1, 25.6 MB)
  short* BT1  = (short*)(h1b + (size_t)N * 64);  // 64 KB
  short* BT2  = BT1 + 2 * D * D;                 // 64 KB
  int* bcur   = (int*)(BT2 + 2 * D * D);         // 256 ints
  int* off    = bcur + 256;                      // N+4 ints (padded for 16B alignment)
  int2* pairs = (int2*)(off + (N + 4));          // E int2 (12.8 MB)
  int4* rec   = (int4*)(pairs + E);              // nbuck*BCAP int4 (31.4 MB), 16B-aligned

  // weight prep + bcur zero (one launch)
  k_prep<<<(4 * D * D + 256 + 255) / 256, 256, 0, stream>>>(W1, Wl1, W2, Wl2, BT1, BT2, bcur);

  // CSR build via two-level bucket sort
  k_bucket<<<(E + C3_EPB - 1) / C3_EPB, 256, 0, stream>>>(src, dst, ew, bcur, rec, E, nbuck);
  k_sort<<<nbuck, 256, 0, stream>>>(rec, bcur, off, pairs, N, nbuck);

  const int mblocks = (N + BM - 1) / BM;
  const int ablocks = (N + 3) / 4;

  // layer 1: support = x@W1 ; h1b = bf16(x@Wloop1 + b1) ; h1b += agg
  k_gemm<false, true, false><<<mblocks, 256, 0, stream>>>(
      x, BT1, b1, nullptr, (unsigned short*)sup, h1b, N);
  k_agg<0><<<ablocks, 256, 0, stream>>>(sup, off, pairs, h1b, N);

  // layer 2: support = h1@W2 ; out = (x + h1@Wloop2 + b2)*0.5 ; out += 0.5*agg
  k_gemm<true, false, true><<<mblocks, 256, 0, stream>>>(
      h1b, BT2, b2, x, (unsigned short*)sup, out, N);
  k_agg<1><<<ablocks, 256, 0, stream>>>(sup, off, pairs, out, N);
}

// Round 6
// 325.305 us; speedup vs baseline: 1.8144x; 1.0626x over previous
//
#include <hip/hip_runtime.h>
#include <hip/hip_bf16.h>
#include <stdint.h>

#define D 128
#define BM 64
#define NB_BITS 9             // 512 nodes per bucket
#define NPB (1 << NB_BITS)
#define BCAP 10240            // max edges/bucket (mean 8163)
#define C3_EPB 4096           // edges per k_bucket block

typedef __attribute__((ext_vector_type(8))) short bf16x8;
typedef __attribute__((ext_vector_type(4))) short short4_t;
typedef __attribute__((ext_vector_type(4))) float f32x4;
typedef unsigned int uint32;

static __device__ __forceinline__ short f2bf(float f) {
  uint32_t u = __builtin_bit_cast(uint32_t, f);
  u += 0x7fffu + ((u >> 16) & 1u);   // round-to-nearest-even
  return (short)(u >> 16);
}

// ---------------- prep: BT1,BT2 bf16 [256][128] = [W|Wloop]^T ; zero bcur ----------------

__global__ void k_prep(const float* __restrict__ W1, const float* __restrict__ Wl1,
                       const float* __restrict__ W2, const float* __restrict__ Wl2,
                       short* __restrict__ BT1, short* __restrict__ BT2,
                       int* __restrict__ bcur) {
  int idx = blockIdx.x * 256 + threadIdx.x;
  if (idx < 2 * D * D) {
    int n = idx >> 7, k = idx & (D - 1);
    float v = (n < D) ? W1[k * D + n] : Wl1[k * D + (n - D)];
    BT1[idx] = f2bf(v);
  } else if (idx < 4 * D * D) {
    int i2 = idx - 2 * D * D;
    int n = i2 >> 7, k = i2 & (D - 1);
    float v = (n < D) ? W2[k * D + n] : Wl2[k * D + (n - D)];
    BT2[i2] = f2bf(v);
  } else if (idx < 4 * D * D + 256) {
    bcur[idx - 4 * D * D] = 0;
  }
}

// ---------------- pass 1: bucket-group edges into 16B records ----------------

__global__ __launch_bounds__(256) void k_bucket(const int* __restrict__ src,
                                                const int* __restrict__ dst,
                                                const float* __restrict__ wgt,
                                                int* __restrict__ bcur,
                                                int4* __restrict__ rec,
                                                int E, int nb) {
  __shared__ int lhist[256];
  __shared__ int lbase[256];
  const int t = threadIdx.x;
  const int e0 = blockIdx.x * C3_EPB;
  if (t < nb) lhist[t] = 0;
  __syncthreads();
  for (int i = t; i < C3_EPB; i += 256) {
    int e = e0 + i;
    if (e < E) atomicAdd(&lhist[dst[e] >> NB_BITS], 1);
  }
  __syncthreads();
  if (t < nb) {
    lbase[t] = atomicAdd(&bcur[t], lhist[t]);
    lhist[t] = 0;                       // becomes local rank cursor
  }
  __syncthreads();
  for (int i = t; i < C3_EPB; i += 256) {
    int e = e0 + i;
    if (e < E) {
      int d = dst[e];
      int b = d >> NB_BITS;
      int r = lbase[b] + atomicAdd(&lhist[b], 1);
      if (r >= BCAP) r = BCAP - 1;      // defensive clamp (statistically unreachable)
      rec[(size_t)b * BCAP + r] =
          make_int4(src[e], __builtin_bit_cast(int, wgt[e]), d, 0);
    }
  }
}

// ---------------- pass 2: per-bucket LDS counting sort -> off[] + pairs[] ----------------

__global__ __launch_bounds__(256) void k_sort(const int4* __restrict__ rec,
                                              const int* __restrict__ bcur,
                                              int* __restrict__ off,
                                              int2* __restrict__ pairs,
                                              int N, int nb) {
  __shared__ int bc[256];
  __shared__ int psum[256];
  __shared__ int lofs[NPB];
  const int t = threadIdx.x;
  const int b = blockIdx.x;

  // scan bucket counts (redundant per block; 256-wide Hillis-Steele)
  int mycnt = (t < nb) ? min(bcur[t], BCAP) : 0;
  bc[t] = mycnt;
  __syncthreads();
  for (int dd = 1; dd < 256; dd <<= 1) {
    int a = (t >= dd) ? bc[t - dd] : 0;
    __syncthreads();
    bc[t] += a;
    __syncthreads();
  }
  const int cntb = min(bcur[b], BCAP);
  const int ebase = bc[b] - cntb;
  const int total = bc[nb - 1];
  const size_t rbase = (size_t)b * BCAP;
  const int n0 = b << NB_BITS;
  const int nn = min(NPB, N - n0);

  // local histogram over the bucket's nodes
  for (int i = t; i < NPB; i += 256) lofs[i] = 0;
  __syncthreads();
  for (int i = t; i < cntb; i += 256)
    atomicAdd(&lofs[rec[rbase + i].z & (NPB - 1)], 1);
  __syncthreads();

  // exclusive scan of 512 counts: 2/thread + 256-wide scan of partials
  int v0 = lofs[2 * t], v1 = lofs[2 * t + 1];
  int sum = v0 + v1;
  psum[t] = sum;
  __syncthreads();
  for (int dd = 1; dd < 256; dd <<= 1) {
    int a = (t >= dd) ? psum[t - dd] : 0;
    __syncthreads();
    psum[t] += a;
    __syncthreads();
  }
  int run = psum[t] - sum;
  lofs[2 * t] = run;
  lofs[2 * t + 1] = run + v0;
  __syncthreads();

  // emit per-node offsets
  for (int i = t; i < nn; i += 256) off[n0 + i] = ebase + lofs[i];
  if (b == nb - 1 && t == 0) off[N] = total;
  __syncthreads();                      // off-emit must finish before lofs is mutated

  // scatter into final sorted order (lofs doubles as cursor array)
  for (int i = t; i < cntb; i += 256) {
    int4 rr = rec[rbase + i];
    int r = atomicAdd(&lofs[rr.z & (NPB - 1)], 1);
    pairs[ebase + r] = make_int2(rr.x, rr.y);
  }
}

// ---------------- fused GEMM: support(bf16) = A@W ; init = A@Wloop + b [+resid, *0.5] ----------------

template<bool ABF16, bool IBF16, bool RESID>
__global__ __launch_bounds__(256) void k_gemm(const void* __restrict__ Ap,
                                              const short* __restrict__ BT,
                                              const float* __restrict__ bias,
                                              const float* __restrict__ resid,
                                              unsigned short* __restrict__ support,
                                              void* __restrict__ initp, int M) {
  __shared__ short As[BM * D];                   // 16 KB, XOR-swizzled
  const int t = threadIdx.x;
  const int l = t & 63;
  const int w = t >> 6;
  const int m0 = blockIdx.x * BM;

  bf16x8 bfrag[4][4];
  const int colbase = w * 64 + (l & 15);
#pragma unroll
  for (int cf = 0; cf < 4; ++cf) {
    const short* p = BT + (colbase + cf * 16) * D + (l >> 4) * 8;
#pragma unroll
    for (int ks = 0; ks < 4; ++ks) bfrag[cf][ks] = *(const bf16x8*)(p + ks * 32);
  }

#pragma unroll
  for (int i = 0; i < 8; ++i) {
    int id = t + i * 256;                        // 0..2047
    int row = id >> 5, c4 = id & 31;
    int gr = m0 + row;
    short4_t s4;
    if (ABF16) {
      if (gr < M) s4 = *(const short4_t*)((const short*)Ap + (size_t)gr * D + c4 * 4);
      else { s4[0] = s4[1] = s4[2] = s4[3] = 0; }
    } else {
      float4 v;
      if (gr < M) v = *(const float4*)((const float*)Ap + (size_t)gr * D + c4 * 4);
      else { v.x = v.y = v.z = v.w = 0.f; }
      s4[0] = f2bf(v.x); s4[1] = f2bf(v.y); s4[2] = f2bf(v.z); s4[3] = f2bf(v.w);
    }
    int sidx = row * D + ((c4 * 4) ^ ((row & 7) << 3));
    *(short4_t*)(As + sidx) = s4;
  }
  __syncthreads();

  f32x4 acc[4][4] = {};                          // [rf][cf]
#pragma unroll
  for (int ks = 0; ks < 4; ++ks) {
    bf16x8 afrag[4];
    int kcol = ks * 32 + (l >> 4) * 8;
#pragma unroll
    for (int rf = 0; rf < 4; ++rf) {
      int row = rf * 16 + (l & 15);
      afrag[rf] = *(const bf16x8*)(As + row * D + (kcol ^ ((row & 7) << 3)));
    }
#pragma unroll
    for (int rf = 0; rf < 4; ++rf)
#pragma unroll
      for (int cf = 0; cf < 4; ++cf)
        acc[rf][cf] = __builtin_amdgcn_mfma_f32_16x16x32_bf16(
            afrag[rf], bfrag[cf][ks], acc[rf][cf], 0, 0, 0);
  }

  // epilogue: waves 0,1 -> support (bf16); waves 2,3 -> init (+bias [+resid]*0.5)
  const bool isInit = (w >= 2);
#pragma unroll
  for (int cf = 0; cf < 4; ++cf) {
    int c = colbase + cf * 16;
    int oc = isInit ? (c - D) : c;
    float bv = isInit ? bias[oc] : 0.f;
#pragma unroll
    for (int rf = 0; rf < 4; ++rf) {
      int rbase = m0 + rf * 16 + (l >> 4) * 4;
#pragma unroll
      for (int j = 0; j < 4; ++j) {
        int r = rbase + j;
        if (r < M) {
          if (isInit) {
            float val = acc[rf][cf][j] + bv;
            if (RESID) val = (val + resid[(size_t)r * D + oc]) * 0.5f;
            if (IBF16) ((unsigned short*)initp)[(size_t)r * D + oc] = (unsigned short)f2bf(val);
            else       ((float*)initp)[(size_t)r * D + oc] = val;
          } else {
            support[(size_t)r * D + oc] = (unsigned short)f2bf(acc[rf][cf][j]);
          }
        }
      }
    }
  }
}

// ---------------- aggregation: io[n] += [0.5*] sum_j bf16(support[src_j])*w_j ----------------
// one wave per node; lane l owns channels 2l,2l+1 (one uint = 2 bf16).
// Edge stream is WAVE-UNIFORM: beg/end, pair values, gather row, and weight are
// forced to SGPRs via readfirstlane -> pair logic on scalar pipe, gather uses
// SGPR-base + fixed l*4 voffset, fma takes weight as SGPR operand.
// 8-edge batches, pair loads pipelined one batch ahead; tail masked by zero weight.

template<int MODE>
__global__ __launch_bounds__(256) void k_agg(const uint32* __restrict__ sup,
                                             const int* __restrict__ off,
                                             const int2* __restrict__ pairs,
                                             void* __restrict__ iop, int N) {
  int node = blockIdx.x * 4 + (threadIdx.x >> 6);
  if (node >= N) return;
  const int l = threadIdx.x & 63;
  const int beg = __builtin_amdgcn_readfirstlane(off[node]);
  const int end = __builtin_amdgcn_readfirstlane(off[node + 1]);
  float ax = 0.f, ay = 0.f;
  const int nbt = (end - beg + 7) >> 3;

  if (nbt > 0) {
    int pr[8], pw[8];
#pragma unroll
    for (int i = 0; i < 8; ++i) {
      int jj = beg + i;
      int jc = jj < end ? jj : beg;
      int2 tt = pairs[jc];
      pr[i] = __builtin_amdgcn_readfirstlane(tt.x);
      pw[i] = __builtin_amdgcn_readfirstlane(jj < end ? tt.y : 0);
    }
    int j = beg + 8;
    for (int b = 1; b < nbt; ++b, j += 8) {
      int nr[8], nw[8];
#pragma unroll
      for (int i = 0; i < 8; ++i) {              // prefetch next batch (scalar)
        int jj = j + i;
        int jc = jj < end ? jj : beg;
        int2 tt = pairs[jc];
        nr[i] = __builtin_amdgcn_readfirstlane(tt.x);
        nw[i] = __builtin_amdgcn_readfirstlane(jj < end ? tt.y : 0);
      }
      uint32 v[8];
#pragma unroll
      for (int i = 0; i < 8; ++i) v[i] = sup[(size_t)(uint32)pr[i] * 64 + l];
#pragma unroll
      for (int i = 0; i < 8; ++i) {
        float w = __builtin_bit_cast(float, pw[i]);
        ax = fmaf(__builtin_bit_cast(float, v[i] << 16), w, ax);
        ay = fmaf(__builtin_bit_cast(float, v[i] & 0xffff0000u), w, ay);
      }
#pragma unroll
      for (int i = 0; i < 8; ++i) { pr[i] = nr[i]; pw[i] = nw[i]; }
    }
    uint32 v[8];
#pragma unroll
    for (int i = 0; i < 8; ++i) v[i] = sup[(size_t)(uint32)pr[i] * 64 + l];
#pragma unroll
    for (int i = 0; i < 8; ++i) {
      float w = __builtin_bit_cast(float, pw[i]);
      ax = fmaf(__builtin_bit_cast(float, v[i] << 16), w, ax);
      ay = fmaf(__builtin_bit_cast(float, v[i] & 0xffff0000u), w, ay);
    }
  }

  size_t o = (size_t)node * 64 + l;
  if (MODE == 0) {
    uint32* io = (uint32*)iop;
    uint32 cur = io[o];
    float vx = __builtin_bit_cast(float, cur << 16) + ax;
    float vy = __builtin_bit_cast(float, cur & 0xffff0000u) + ay;
    io[o] = ((uint32)(unsigned short)f2bf(vy) << 16) | (unsigned short)f2bf(vx);
  } else {
    float2* io = (float2*)iop;
    float2 v = io[o];
    v.x = fmaf(0.5f, ax, v.x);
    v.y = fmaf(0.5f, ay, v.y);
    io[o] = v;
  }
}

// ---------------- launch ----------------

extern "C" void kernel_launch(void* const* d_in, const int* in_sizes, int n_in,
                              void* d_out, int out_size, void* d_ws, size_t ws_size,
                              hipStream_t stream) {
  const float* x   = (const float*)d_in[0];
  const int*   ei  = (const int*)d_in[1];
  const float* ew  = (const float*)d_in[2];
  const float* W1  = (const float*)d_in[3];
  const float* Wl1 = (const float*)d_in[4];
  const float* b1  = (const float*)d_in[5];
  const float* W2  = (const float*)d_in[6];
  const float* Wl2 = (const float*)d_in[7];
  const float* b2  = (const float*)d_in[8];
  float* out = (float*)d_out;

  const int N = in_sizes[0] / D;
  const int E = in_sizes[1] / 2;
  const int* src = ei;
  const int* dst = ei + E;
  const int nbuck = (N + NPB - 1) >> NB_BITS;           // 196

  // workspace layout (~96 MB)
  uint32* sup = (uint32*)d_ws;                   // N*64 u32 (bf16 support, 25.6 MB)
  uint32* h1b = sup + (size_t)N * 64;            // N*64 u32 (bf16 h1, 25.6 MB)
  short* BT1  = (short*)(h1b + (size_t)N * 64);  // 64 KB
  short* BT2  = BT1 + 2 * D * D;                 // 64 KB
  int* bcur   = (int*)(BT2 + 2 * D * D);         // 256 ints
  int* off    = bcur + 256;                      // N+4 ints (padded for 16B alignment)
  int2* pairs = (int2*)(off + (N + 4));          // E int2 (12.8 MB)
  int4* rec   = (int4*)(pairs + E);              // nbuck*BCAP int4 (31.4 MB), 16B-aligned

  // weight prep + bcur zero (one launch)
  k_prep<<<(4 * D * D + 256 + 255) / 256, 256, 0, stream>>>(W1, Wl1, W2, Wl2, BT1, BT2, bcur);

  // CSR build via two-level bucket sort
  k_bucket<<<(E + C3_EPB - 1) / C3_EPB, 256, 0, stream>>>(src, dst, ew, bcur, rec, E, nbuck);
  k_sort<<<nbuck, 256, 0, stream>>>(rec, bcur, off, pairs, N, nbuck);

  const int mblocks = (N + BM - 1) / BM;
  const int ablocks = (N + 3) / 4;

  // layer 1: support = x@W1 ; h1b = bf16(x@Wloop1 + b1) ; h1b += agg
  k_gemm<false, true, false><<<mblocks, 256, 0, stream>>>(
      x, BT1, b1, nullptr, (unsigned short*)sup, h1b, N);
  k_agg<0><<<ablocks, 256, 0, stream>>>(sup, off, pairs, h1b, N);

  // layer 2: support = h1@W2 ; out = (x + h1@Wloop2 + b2)*0.5 ; out += 0.5*agg
  k_gemm<true, false, true><<<mblocks, 256, 0, stream>>>(
      h1b, BT2, b2, x, (unsigned short*)sup, out, N);
  k_agg<1><<<ablocks, 256, 0, stream>>>(sup, off, pairs, out, N);
}

// Round 7
// 267.969 us; speedup vs baseline: 2.2026x; 1.2140x over previous
//
#include <hip/hip_runtime.h>
#include <hip/hip_bf16.h>
#include <stdint.h>

#define D 128
#define BM 64
#define NB_BITS 9             // 512 nodes per bucket
#define NPB (1 << NB_BITS)
#define BCAP 10240            // max edges/bucket (mean 8163)
#define C3_EPB 4096           // edges per k_bucket block

typedef __attribute__((ext_vector_type(8))) short bf16x8;
typedef __attribute__((ext_vector_type(4))) short short4_t;
typedef __attribute__((ext_vector_type(4))) float f32x4;
typedef unsigned int uint32;

static __device__ __forceinline__ short f2bf(float f) {
  uint32_t u = __builtin_bit_cast(uint32_t, f);
  u += 0x7fffu + ((u >> 16) & 1u);   // round-to-nearest-even
  return (short)(u >> 16);
}

static __device__ __forceinline__ uint32 pk2bf(float a, float b) {
  return ((uint32)(unsigned short)f2bf(b) << 16) | (uint32)(unsigned short)f2bf(a);
}

// ---------------- prep: BT1,BT2 bf16 [256][128] = [W|Wloop]^T ; zero bcur ----------------

__global__ void k_prep(const float* __restrict__ W1, const float* __restrict__ Wl1,
                       const float* __restrict__ W2, const float* __restrict__ Wl2,
                       short* __restrict__ BT1, short* __restrict__ BT2,
                       int* __restrict__ bcur) {
  int idx = blockIdx.x * 256 + threadIdx.x;
  if (idx < 2 * D * D) {
    int n = idx >> 7, k = idx & (D - 1);
    float v = (n < D) ? W1[k * D + n] : Wl1[k * D + (n - D)];
    BT1[idx] = f2bf(v);
  } else if (idx < 4 * D * D) {
    int i2 = idx - 2 * D * D;
    int n = i2 >> 7, k = i2 & (D - 1);
    float v = (n < D) ? W2[k * D + n] : Wl2[k * D + (n - D)];
    BT2[i2] = f2bf(v);
  } else if (idx < 4 * D * D + 256) {
    bcur[idx - 4 * D * D] = 0;
  }
}

// ---------------- pass 1: bucket-group edges into 16B records ----------------

__global__ __launch_bounds__(256) void k_bucket(const int* __restrict__ src,
                                                const int* __restrict__ dst,
                                                const float* __restrict__ wgt,
                                                int* __restrict__ bcur,
                                                int4* __restrict__ rec,
                                                int E, int nb) {
  __shared__ int lhist[256];
  __shared__ int lbase[256];
  const int t = threadIdx.x;
  const int e0 = blockIdx.x * C3_EPB;
  if (t < nb) lhist[t] = 0;
  __syncthreads();
  for (int i = t; i < C3_EPB; i += 256) {
    int e = e0 + i;
    if (e < E) atomicAdd(&lhist[dst[e] >> NB_BITS], 1);
  }
  __syncthreads();
  if (t < nb) {
    lbase[t] = atomicAdd(&bcur[t], lhist[t]);
    lhist[t] = 0;                       // becomes local rank cursor
  }
  __syncthreads();
  for (int i = t; i < C3_EPB; i += 256) {
    int e = e0 + i;
    if (e < E) {
      int d = dst[e];
      int b = d >> NB_BITS;
      int r = lbase[b] + atomicAdd(&lhist[b], 1);
      if (r >= BCAP) r = BCAP - 1;      // defensive clamp (statistically unreachable)
      rec[(size_t)b * BCAP + r] =
          make_int4(src[e], __builtin_bit_cast(int, wgt[e]), d, 0);
    }
  }
}

// ---------------- pass 2: per-bucket LDS counting sort -> off[] + pairs[] ----------------

__global__ __launch_bounds__(256) void k_sort(const int4* __restrict__ rec,
                                              const int* __restrict__ bcur,
                                              int* __restrict__ off,
                                              int2* __restrict__ pairs,
                                              int N, int nb) {
  __shared__ int bc[256];
  __shared__ int psum[256];
  __shared__ int lofs[NPB];
  const int t = threadIdx.x;
  const int b = blockIdx.x;

  // scan bucket counts (redundant per block; 256-wide Hillis-Steele)
  int mycnt = (t < nb) ? min(bcur[t], BCAP) : 0;
  bc[t] = mycnt;
  __syncthreads();
  for (int dd = 1; dd < 256; dd <<= 1) {
    int a = (t >= dd) ? bc[t - dd] : 0;
    __syncthreads();
    bc[t] += a;
    __syncthreads();
  }
  const int cntb = min(bcur[b], BCAP);
  const int ebase = bc[b] - cntb;
  const int total = bc[nb - 1];
  const size_t rbase = (size_t)b * BCAP;
  const int n0 = b << NB_BITS;
  const int nn = min(NPB, N - n0);

  // local histogram over the bucket's nodes
  for (int i = t; i < NPB; i += 256) lofs[i] = 0;
  __syncthreads();
  for (int i = t; i < cntb; i += 256)
    atomicAdd(&lofs[rec[rbase + i].z & (NPB - 1)], 1);
  __syncthreads();

  // exclusive scan of 512 counts: 2/thread + 256-wide scan of partials
  int v0 = lofs[2 * t], v1 = lofs[2 * t + 1];
  int sum = v0 + v1;
  psum[t] = sum;
  __syncthreads();
  for (int dd = 1; dd < 256; dd <<= 1) {
    int a = (t >= dd) ? psum[t - dd] : 0;
    __syncthreads();
    psum[t] += a;
    __syncthreads();
  }
  int run = psum[t] - sum;
  lofs[2 * t] = run;
  lofs[2 * t + 1] = run + v0;
  __syncthreads();

  // emit per-node offsets
  for (int i = t; i < nn; i += 256) off[n0 + i] = ebase + lofs[i];
  if (b == nb - 1 && t == 0) off[N] = total;
  __syncthreads();                      // off-emit must finish before lofs is mutated

  // scatter into final sorted order (lofs doubles as cursor array)
  for (int i = t; i < cntb; i += 256) {
    int4 rr = rec[rbase + i];
    int r = atomicAdd(&lofs[rr.z & (NPB - 1)], 1);
    pairs[ebase + r] = make_int2(rr.x, rr.y);
  }
}

// ---------------- fused GEMM: support(bf16) = A@W ; init = A@Wloop + b [+resid, *0.5] ----------------
// MFMA operands SWAPPED (mfma(b,a,acc)) -> acc holds C^T fragments: lane owns
// row m = rf*16+(l&15), 4 CONSECUTIVE cols n = cf*16+(l>>4)*4 + 0..3.
// Epilogue: dwordx2 (4x bf16) / dwordx4 (4x f32) stores, float4 bias/resid reads.

template<bool ABF16, bool IBF16, bool RESID>
__global__ __launch_bounds__(256) void k_gemm(const void* __restrict__ Ap,
                                              const short* __restrict__ BT,
                                              const float* __restrict__ bias,
                                              const float* __restrict__ resid,
                                              unsigned short* __restrict__ support,
                                              void* __restrict__ initp, int M) {
  __shared__ short As[BM * D];                   // 16 KB, XOR-swizzled
  const int t = threadIdx.x;
  const int l = t & 63;
  const int w = t >> 6;
  const int lm = l & 15;
  const int lg = l >> 4;
  const int m0 = blockIdx.x * BM;
  const bool full = (m0 + BM <= M);

  // ---- issue A loads first (HBM long pole), clamped indices (no branches) ----
  short4_t aregs[8];
  float4 aregf[8];
#pragma unroll
  for (int i = 0; i < 8; ++i) {
    int id = t + i * 256;                        // 0..2047
    int row = id >> 5, c4 = id & 31;
    int gr = m0 + row; if (gr >= M) gr = M - 1;
    if (ABF16) aregs[i] = *(const short4_t*)((const short*)Ap + (size_t)gr * D + c4 * 4);
    else       aregf[i] = *(const float4*)((const float*)Ap + (size_t)gr * D + c4 * 4);
  }

  // ---- B fragments (L2-hot 64KB) ----
  bf16x8 bfrag[4][4];
  const int colbase = w * 64 + lm;
#pragma unroll
  for (int cf = 0; cf < 4; ++cf) {
    const short* p = BT + (colbase + cf * 16) * D + lg * 8;
#pragma unroll
    for (int ks = 0; ks < 4; ++ks) bfrag[cf][ks] = *(const bf16x8*)(p + ks * 32);
  }

  // ---- convert + LDS write (swizzled: short index ^= (row&7)<<3) ----
#pragma unroll
  for (int i = 0; i < 8; ++i) {
    int id = t + i * 256;
    int row = id >> 5, c4 = id & 31;
    short4_t s4;
    if (ABF16) s4 = aregs[i];
    else {
      float4 v = aregf[i];
      s4[0] = f2bf(v.x); s4[1] = f2bf(v.y); s4[2] = f2bf(v.z); s4[3] = f2bf(v.w);
    }
    int sidx = row * D + ((c4 * 4) ^ ((row & 7) << 3));
    *(short4_t*)(As + sidx) = s4;
  }
  __syncthreads();

  f32x4 acc[4][4] = {};                          // [rf][cf], C^T frags
#pragma unroll
  for (int ks = 0; ks < 4; ++ks) {
    bf16x8 afrag[4];
    int kcol = ks * 32 + lg * 8;
#pragma unroll
    for (int rf = 0; rf < 4; ++rf) {
      int row = rf * 16 + lm;
      afrag[rf] = *(const bf16x8*)(As + row * D + (kcol ^ ((row & 7) << 3)));
    }
#pragma unroll
    for (int rf = 0; rf < 4; ++rf)
#pragma unroll
      for (int cf = 0; cf < 4; ++cf)
        acc[rf][cf] = __builtin_amdgcn_mfma_f32_16x16x32_bf16(
            bfrag[cf][ks], afrag[rf], acc[rf][cf], 0, 0, 0);   // SWAPPED -> C^T
  }

  // ---- epilogue: waves 0,1 -> support (bf16); waves 2,3 -> init ----
  const bool isInit = (w >= 2);
  const int wcol = (w & 1) * 64;                 // column base within the 128-wide output

  if (!isInit) {
#pragma unroll
    for (int rf = 0; rf < 4; ++rf) {
      int m = m0 + rf * 16 + lm;
#pragma unroll
      for (int cf = 0; cf < 4; ++cf) {
        int nb = wcol + cf * 16 + lg * 4;
        f32x4 a = acc[rf][cf];
        uint2 pk = make_uint2(pk2bf(a[0], a[1]), pk2bf(a[2], a[3]));
        if (full || m < M)
          *(uint2*)((uint32*)support + (size_t)m * 64 + (nb >> 1)) = pk;
      }
    }
  } else {
    float4 bv4[4];
#pragma unroll
    for (int cf = 0; cf < 4; ++cf)
      bv4[cf] = *(const float4*)(bias + wcol + cf * 16 + lg * 4);
#pragma unroll
    for (int rf = 0; rf < 4; ++rf) {
      int m = m0 + rf * 16 + lm;
      bool ok = full || m < M;
#pragma unroll
      for (int cf = 0; cf < 4; ++cf) {
        int nb = wcol + cf * 16 + lg * 4;
        f32x4 a = acc[rf][cf];
        float4 v;
        v.x = a[0] + bv4[cf].x; v.y = a[1] + bv4[cf].y;
        v.z = a[2] + bv4[cf].z; v.w = a[3] + bv4[cf].w;
        if (RESID) {
          if (ok) {
            float4 xr = *(const float4*)(resid + (size_t)m * D + nb);
            v.x = (v.x + xr.x) * 0.5f; v.y = (v.y + xr.y) * 0.5f;
            v.z = (v.z + xr.z) * 0.5f; v.w = (v.w + xr.w) * 0.5f;
          }
        }
        if (ok) {
          if (IBF16) {
            uint2 pk = make_uint2(pk2bf(v.x, v.y), pk2bf(v.z, v.w));
            *(uint2*)((uint32*)initp + (size_t)m * 64 + (nb >> 1)) = pk;
          } else {
            *(float4*)((float*)initp + (size_t)m * D + nb) = v;
          }
        }
      }
    }
  }
}

// ---------------- aggregation: io[n] += [0.5*] sum_j bf16(support[src_j])*w_j ----------------
// one wave per node; edge stream scalarized via readfirstlane; 8-edge batches,
// pair loads pipelined one batch ahead; tail masked by zero weight.

template<int MODE>
__global__ __launch_bounds__(256) void k_agg(const uint32* __restrict__ sup,
                                             const int* __restrict__ off,
                                             const int2* __restrict__ pairs,
                                             void* __restrict__ iop, int N) {
  int node = blockIdx.x * 4 + (threadIdx.x >> 6);
  if (node >= N) return;
  const int l = threadIdx.x & 63;
  const int beg = __builtin_amdgcn_readfirstlane(off[node]);
  const int end = __builtin_amdgcn_readfirstlane(off[node + 1]);
  float ax = 0.f, ay = 0.f;
  const int nbt = (end - beg + 7) >> 3;

  if (nbt > 0) {
    int pr[8], pw[8];
#pragma unroll
    for (int i = 0; i < 8; ++i) {
      int jj = beg + i;
      int jc = jj < end ? jj : beg;
      int2 tt = pairs[jc];
      pr[i] = __builtin_amdgcn_readfirstlane(tt.x);
      pw[i] = __builtin_amdgcn_readfirstlane(jj < end ? tt.y : 0);
    }
    int j = beg + 8;
    for (int b = 1; b < nbt; ++b, j += 8) {
      int nr[8], nw[8];
#pragma unroll
      for (int i = 0; i < 8; ++i) {              // prefetch next batch (scalar)
        int jj = j + i;
        int jc = jj < end ? jj : beg;
        int2 tt = pairs[jc];
        nr[i] = __builtin_amdgcn_readfirstlane(tt.x);
        nw[i] = __builtin_amdgcn_readfirstlane(jj < end ? tt.y : 0);
      }
      uint32 v[8];
#pragma unroll
      for (int i = 0; i < 8; ++i) v[i] = sup[(size_t)(uint32)pr[i] * 64 + l];
#pragma unroll
      for (int i = 0; i < 8; ++i) {
        float w = __builtin_bit_cast(float, pw[i]);
        ax = fmaf(__builtin_bit_cast(float, v[i] << 16), w, ax);
        ay = fmaf(__builtin_bit_cast(float, v[i] & 0xffff0000u), w, ay);
      }
#pragma unroll
      for (int i = 0; i < 8; ++i) { pr[i] = nr[i]; pw[i] = nw[i]; }
    }
    uint32 v[8];
#pragma unroll
    for (int i = 0; i < 8; ++i) v[i] = sup[(size_t)(uint32)pr[i] * 64 + l];
#pragma unroll
    for (int i = 0; i < 8; ++i) {
      float w = __builtin_bit_cast(float, pw[i]);
      ax = fmaf(__builtin_bit_cast(float, v[i] << 16), w, ax);
      ay = fmaf(__builtin_bit_cast(float, v[i] & 0xffff0000u), w, ay);
    }
  }

  size_t o = (size_t)node * 64 + l;
  if (MODE == 0) {
    uint32* io = (uint32*)iop;
    uint32 cur = io[o];
    float vx = __builtin_bit_cast(float, cur << 16) + ax;
    float vy = __builtin_bit_cast(float, cur & 0xffff0000u) + ay;
    io[o] = ((uint32)(unsigned short)f2bf(vy) << 16) | (unsigned short)f2bf(vx);
  } else {
    float2* io = (float2*)iop;
    float2 v = io[o];
    v.x = fmaf(0.5f, ax, v.x);
    v.y = fmaf(0.5f, ay, v.y);
    io[o] = v;
  }
}

// ---------------- launch ----------------

extern "C" void kernel_launch(void* const* d_in, const int* in_sizes, int n_in,
                              void* d_out, int out_size, void* d_ws, size_t ws_size,
                              hipStream_t stream) {
  const float* x   = (const float*)d_in[0];
  const int*   ei  = (const int*)d_in[1];
  const float* ew  = (const float*)d_in[2];
  const float* W1  = (const float*)d_in[3];
  const float* Wl1 = (const float*)d_in[4];
  const float* b1  = (const float*)d_in[5];
  const float* W2  = (const float*)d_in[6];
  const float* Wl2 = (const float*)d_in[7];
  const float* b2  = (const float*)d_in[8];
  float* out = (float*)d_out;

  const int N = in_sizes[0] / D;
  const int E = in_sizes[1] / 2;
  const int* src = ei;
  const int* dst = ei + E;
  const int nbuck = (N + NPB - 1) >> NB_BITS;           // 196

  // workspace layout (~96 MB)
  uint32* sup = (uint32*)d_ws;                   // N*64 u32 (bf16 support, 25.6 MB)
  uint32* h1b = sup + (size_t)N * 64;            // N*64 u32 (bf16 h1, 25.6 MB)
  short* BT1  = (short*)(h1b + (size_t)N * 64);  // 64 KB
  short* BT2  = BT1 + 2 * D * D;                 // 64 KB
  int* bcur   = (int*)(BT2 + 2 * D * D);         // 256 ints
  int* off    = bcur + 256;                      // N+4 ints (padded for 16B alignment)
  int2* pairs = (int2*)(off + (N + 4));          // E int2 (12.8 MB)
  int4* rec   = (int4*)(pairs + E);              // nbuck*BCAP int4 (31.4 MB), 16B-aligned

  // weight prep + bcur zero (one launch)
  k_prep<<<(4 * D * D + 256 + 255) / 256, 256, 0, stream>>>(W1, Wl1, W2, Wl2, BT1, BT2, bcur);

  // CSR build via two-level bucket sort
  k_bucket<<<(E + C3_EPB - 1) / C3_EPB, 256, 0, stream>>>(src, dst, ew, bcur, rec, E, nbuck);
  k_sort<<<nbuck, 256, 0, stream>>>(rec, bcur, off, pairs, N, nbuck);

  const int mblocks = (N + BM - 1) / BM;
  const int ablocks = (N + 3) / 4;

  // layer 1: support = x@W1 ; h1b = bf16(x@Wloop1 + b1) ; h1b += agg
  k_gemm<false, true, false><<<mblocks, 256, 0, stream>>>(
      x, BT1, b1, nullptr, (unsigned short*)sup, h1b, N);
  k_agg<0><<<ablocks, 256, 0, stream>>>(sup, off, pairs, h1b, N);

  // layer 2: support = h1@W2 ; out = (x + h1@Wloop2 + b2)*0.5 ; out += 0.5*agg
  k_gemm<true, false, true><<<mblocks, 256, 0, stream>>>(
      h1b, BT2, b2, x, (unsigned short*)sup, out, N);
  k_agg<1><<<ablocks, 256, 0, stream>>>(sup, off, pairs, out, N);
}